// Round 12
// baseline (332.265 us; speedup 1.0000x reference)
//
#include <hip/hip_runtime.h>

typedef unsigned short u16;
typedef unsigned int u32;
typedef u16 u16x4 __attribute__((ext_vector_type(4)));
typedef u16 u16x8 __attribute__((ext_vector_type(8)));
typedef u32 u32x4 __attribute__((ext_vector_type(4)));
typedef float f32x4 __attribute__((ext_vector_type(4)));
typedef float f32x16 __attribute__((ext_vector_type(16)));
typedef __bf16 bf16x2 __attribute__((ext_vector_type(2)));
typedef __bf16 bf16x8 __attribute__((ext_vector_type(8)));

#define GLOAD16(gp, lp)                                             \
  __builtin_amdgcn_global_load_lds(                                 \
      (const __attribute__((address_space(1))) void*)(gp),          \
      (__attribute__((address_space(3))) void*)(lp), 16, 0, 0)

__device__ __forceinline__ u16 f2bf(float f) {
  unsigned int u = __builtin_bit_cast(unsigned int, f);
  u += 0x7FFFu + ((u >> 16) & 1u);
  return (u16)(u >> 16);
}
__device__ __forceinline__ float bf2f(u16 h) {
  return __builtin_bit_cast(float, (u32)h << 16);
}

// ---------------------------------------------------------------- f32 -> bf16
__global__ __launch_bounds__(256) void f2b_kernel(const float* __restrict__ in,
                                                  u16* __restrict__ out, int n4) {
  int i = blockIdx.x * 256 + threadIdx.x;
  if (i < n4) {
    f32x4 v = *(const f32x4*)(in + (size_t)i * 4);
    u16x4 o;
    o[0] = f2bf(v[0]); o[1] = f2bf(v[1]); o[2] = f2bf(v[2]); o[3] = f2bf(v[3]);
    *(u16x4*)(out + (size_t)i * 4) = o;
  }
}

// all 4 weight matrices in one launch; dst regions contiguous (1M elems each)
__global__ __launch_bounds__(256) void f2bw_kernel(const float* __restrict__ s0,
    const float* __restrict__ s1, const float* __restrict__ s2,
    const float* __restrict__ s3, u16* __restrict__ dst) {
  const int y = blockIdx.y;
  const float* s = (y == 0) ? s0 : ((y == 1) ? s1 : ((y == 2) ? s2 : s3));
  int i = blockIdx.x * 256 + threadIdx.x;
  f32x4 v = *(const f32x4*)(s + (size_t)i * 4);
  u16x4 o;
  o[0] = f2bf(v[0]); o[1] = f2bf(v[1]); o[2] = f2bf(v[2]); o[3] = f2bf(v[3]);
  *(u16x4*)(dst + (size_t)y * 1048576 + (size_t)i * 4) = o;
}

// --------------------------------------------- NT GEMM core: C = A * W^T
// 128x128 tile, BK=32, 256 thr (4 waves). 3-buffer counted-vmcnt pipeline.
__device__ __forceinline__ void gemm_core(const u16* __restrict__ A,
                                          const u16* __restrict__ W,
                                          int bm0, int bn0,
                                          u16* ldsA, u16* ldsB,
                                          f32x4 acc[4][4]) {
  const int tid = threadIdx.x;
  const int l = tid & 63;
  const int lr = l & 15, lk = l >> 4;
  const int w = tid >> 6;
  const int wr = w >> 1, wc = w & 1;
  const int srow = tid >> 2, sko = (tid & 3) << 3;
  auto stage = [&](int kt, int buf) {  // 4 VMEM loads per thread
#pragma unroll
    for (int it = 0; it < 2; ++it) {
      int row = it * 64 + srow;
      GLOAD16(A + (size_t)(bm0 + row) * 1024 + kt * 32 + sko,
              ldsA + buf * 4096 + (it * 256 + tid) * 8);
      GLOAD16(W + (size_t)(bn0 + row) * 1024 + kt * 32 + sko,
              ldsB + buf * 4096 + (it * 256 + tid) * 8);
    }
  };
  stage(0, 0);
  stage(1, 1);
  int cur = 0, nx2 = 2;
  for (int kt = 0; kt < 32; ++kt) {
    if (kt < 31) asm volatile("s_waitcnt vmcnt(4)" ::: "memory");
    else         asm volatile("s_waitcnt vmcnt(0)" ::: "memory");
    __builtin_amdgcn_s_barrier();
    __builtin_amdgcn_sched_barrier(0);
    if (kt + 2 < 32) stage(kt + 2, nx2);
    const u16* lA = ldsA + cur * 4096;
    const u16* lB = ldsB + cur * 4096;
    bf16x8 af[4], bfr[4];
#pragma unroll
    for (int m = 0; m < 4; ++m)
      af[m] = *(const bf16x8*)(lA + (wr * 64 + m * 16 + lr) * 32 + lk * 8);
#pragma unroll
    for (int n = 0; n < 4; ++n)
      bfr[n] = *(const bf16x8*)(lB + (wc * 64 + n * 16 + lr) * 32 + lk * 8);
#pragma unroll
    for (int m = 0; m < 4; ++m)
#pragma unroll
      for (int n = 0; n < 4; ++n)
        acc[m][n] = __builtin_amdgcn_mfma_f32_16x16x32_bf16(af[m], bfr[n], acc[m][n], 0, 0, 0);
    cur = (cur == 2) ? 0 : cur + 1;
    nx2 = (nx2 == 2) ? 0 : nx2 + 1;
  }
}

// --------------------------------------------- fused QKV projection
// z=0: Q -> Qb rows; z=1: K -> Kb rows; z=2: V -> V-frag [bh][t][ks][half][lane][8]
__global__ __launch_bounds__(256) void qkv_gemm(const u16* __restrict__ xb,
    const u16* __restrict__ wq, const u16* __restrict__ wk, const u16* __restrict__ wv,
    const float* __restrict__ bq, const float* __restrict__ bk, const float* __restrict__ bv,
    u16* __restrict__ Qb, u16* __restrict__ Kb, u16* __restrict__ Vf) {
  __shared__ u16 ldsA[3 * 4096];
  __shared__ u16 ldsB[3 * 4096];
  const int z = blockIdx.z;
  const u16* W = (z == 0) ? wq : ((z == 1) ? wk : wv);
  const float* bias = (z == 0) ? bq : ((z == 1) ? bk : bv);
  const int bm0 = blockIdx.x * 128, bn0 = blockIdx.y * 128;
  const f32x4 zf = {0.f, 0.f, 0.f, 0.f};
  f32x4 acc[4][4];
#pragma unroll
  for (int m = 0; m < 4; ++m)
#pragma unroll
    for (int n = 0; n < 4; ++n) acc[m][n] = zf;
  gemm_core(xb, W, bm0, bn0, ldsA, ldsB, acc);
  const int tid = threadIdx.x, l = tid & 63, lr = l & 15, lk = l >> 4;
  const int w = tid >> 6, wr = w >> 1, wc = w & 1;
  float bcol[4];
#pragma unroll
  for (int n = 0; n < 4; ++n) bcol[n] = bias[bn0 + wc * 64 + n * 16 + lr];
  if (z < 2) {
    u16* outp = z ? Kb : Qb;
#pragma unroll
    for (int m = 0; m < 4; ++m)
#pragma unroll
      for (int n = 0; n < 4; ++n)
#pragma unroll
        for (int r = 0; r < 4; ++r) {
          int row = bm0 + wr * 64 + m * 16 + lk * 4 + r;
          int col = bn0 + wc * 64 + n * 16 + lr;
          outp[(size_t)row * 1024 + col] = f2bf(acc[m][n][r] + bcol[n]);
        }
  } else {
    // V-frag: element (hd, key): t=key>>6, kin=key&63, ks=kin>>4, hi=(kin>>3)&1,
    // j=kin&7, vhalf=hd>>5, lq=hd&31.
#pragma unroll
    for (int m = 0; m < 4; ++m)
#pragma unroll
      for (int n = 0; n < 4; ++n) {
        int row = bm0 + wr * 64 + m * 16 + lk * 4;   // key base (r = 0..3)
        int col = bn0 + wc * 64 + n * 16 + lr;
        int b = row >> 11, sf = row & 2047, hh = col >> 6, hd = col & 63;
        int t = sf >> 6, kin = sf & 63;
        int ks = kin >> 4, hiv = (kin >> 3) & 1, j0 = kin & 7;
        int vhalf = hd >> 5, lq = hd & 31;
        u16x4 o;
#pragma unroll
        for (int r = 0; r < 4; ++r) o[r] = f2bf(acc[m][n][r] + bcol[n]);
        size_t addr = (size_t)(b * 16 + hh) * 131072 +
                      (size_t)(((t * 4 + ks) * 2 + vhalf)) * 512 +
                      ((hiv << 5) + lq) * 8 + j0;
        *(u16x4*)(Vf + addr) = o;
      }
  }
}

// --------------------------------------------- output projection
__global__ __launch_bounds__(256) void proj_gemm(const u16* __restrict__ ctx,
    const u16* __restrict__ wo, const float* __restrict__ bo, float* __restrict__ out) {
  __shared__ u16 ldsA[3 * 4096];
  __shared__ u16 ldsB[3 * 4096];
  const int bm0 = blockIdx.x * 128, bn0 = blockIdx.y * 128;
  const f32x4 zf = {0.f, 0.f, 0.f, 0.f};
  f32x4 acc[4][4];
#pragma unroll
  for (int m = 0; m < 4; ++m)
#pragma unroll
    for (int n = 0; n < 4; ++n) acc[m][n] = zf;
  gemm_core(ctx, wo, bm0, bn0, ldsA, ldsB, acc);
  const int tid = threadIdx.x, l = tid & 63, lr = l & 15, lk = l >> 4;
  const int w = tid >> 6, wr = w >> 1, wc = w & 1;
  float bcol[4];
#pragma unroll
  for (int n = 0; n < 4; ++n) bcol[n] = bo[bn0 + wc * 64 + n * 16 + lr];
#pragma unroll
  for (int m = 0; m < 4; ++m)
#pragma unroll
    for (int n = 0; n < 4; ++n)
#pragma unroll
      for (int r = 0; r < 4; ++r) {
        int row = bm0 + wr * 64 + m * 16 + lk * 4 + r;
        int col = bn0 + wc * 64 + n * 16 + lr;
        out[(size_t)row * 1024 + col] = acc[m][n][r] + bcol[n];
      }
}

// --------------------------------------------- RMSNorm + RoPE -> fragment layouts
// which==0 (q): fold 0.125*log2(e); Q-frag [bh][q>>5][hs][lane][8]
// which==1 (k): K-frag [bh][t][hs][khalf][lane][8]
__global__ __launch_bounds__(256) void rmsrope(const u16* __restrict__ Qb,
    const u16* __restrict__ Kb, const float* __restrict__ gq, const float* __restrict__ gk,
    const float* __restrict__ fc, const float* __restrict__ fs,
    u16* __restrict__ Qf, u16* __restrict__ Kf) {
  const int row = blockIdx.x;
  const int which = blockIdx.y;
  const u16* src = (which ? Kb : Qb) + (size_t)row * 1024;
  const float* g = which ? gk : gq;
  const int t = threadIdx.x;
  u16x4 raw = *(const u16x4*)(src + t * 4);
  float v0 = bf2f(raw[0]), v1 = bf2f(raw[1]), v2 = bf2f(raw[2]), v3 = bf2f(raw[3]);
  float ss = v0 * v0 + v1 * v1 + v2 * v2 + v3 * v3;
#pragma unroll
  for (int mm = 1; mm < 64; mm <<= 1) ss += __shfl_xor(ss, mm);
  __shared__ float red[4];
  if ((t & 63) == 0) red[t >> 6] = ss;
  __syncthreads();
  float rstd = rsqrtf((red[0] + red[1] + red[2] + red[3]) * (1.0f / 1024.0f) + 1e-6f);
  if (!which) rstd *= 0.18033688011112042f;   // 0.125 * log2(e) folded into q
  int d = t * 4, hh = d >> 6, dh = d & 63, p = dh >> 1;
  int s = row & 2047, b = row >> 11;
  float c0 = fc[(s << 5) + p], s0 = fs[(s << 5) + p];
  float c1 = fc[(s << 5) + p + 1], s1 = fs[(s << 5) + p + 1];
  float x0 = v0 * rstd * g[d];
  float x1 = v1 * rstd * g[d + 1];
  float x2 = v2 * rstd * g[d + 2];
  float x3 = v3 * rstd * g[d + 3];
  u16x4 o;
  o[0] = f2bf(x0 * c0 - x1 * s0);
  o[1] = f2bf(x0 * s0 + x1 * c0);
  o[2] = f2bf(x2 * c1 - x3 * s1);
  o[3] = f2bf(x2 * s1 + x3 * c1);
  const size_t base = (size_t)(b * 16 + hh) * 131072;
  const int hs = dh >> 4, hi = (dh >> 3) & 1, j0 = dh & 7;
  size_t addr;
  if (!which) {
    addr = base + (size_t)((s >> 5) * 4 + hs) * 512 + ((hi << 5) + (s & 31)) * 8 + j0;
  } else {
    addr = base + (size_t)(((s >> 6) * 4 + hs) * 2 + ((s >> 5) & 1)) * 512 +
           ((hi << 5) + (s & 31)) * 8 + j0;
  }
  *(u16x4*)((which ? Kf : Qf) + addr) = o;
}

// --------------------------------------------- flash attention (non-causal)
// 1024 blocks x 256 thr (4 waves). Each block owns 64 q-rows; waves 0,1 =
// q-halves x k-tiles 0..15, waves 2,3 = q-halves x k-tiles 16..31. Max-free
// softmax -> additive combine via one LDS exchange. 4 blocks/CU => 4 waves/
// SIMD (the R11 lesson: keep 256-thr blocks so VGPR stays ~110, no spill).
__global__ __launch_bounds__(256, 4) void attn_kernel(const u16* __restrict__ Qf,
    const u16* __restrict__ Kf, const u16* __restrict__ Vf, u16* __restrict__ ctx) {
  __shared__ float cmb[2][64][33];   // combine: O0(16)+O1(16)+lsum
  const int tid = threadIdx.x;
  const int w = tid >> 6, l = tid & 63;
  const int wh = w & 1, ws = w >> 1;          // q-half, k-split
  const int lq = l & 31, hi = l >> 5;
  const bool hiB = (hi != 0);
  // 1024 = 8 (xcd) x ... : qb = (id>>3)&31 (64-row block), hb = (id&7)|((id>>8)<<3)
  const int id = blockIdx.x;
  const int qb = (id >> 3) & 31;
  const int hb = (id & 7) | ((id >> 8) << 3);
  const int h = hb & 15, b = hb >> 4;
  const int bh = b * 16 + h;
  const u16* Qp = Qf + (size_t)bh * 131072;
  const u16* Kp = Kf + (size_t)bh * 131072;
  const u16* Vp = Vf + (size_t)bh * 131072;
  bf16x8 qf[4];
#pragma unroll
  for (int hs = 0; hs < 4; ++hs)
    qf[hs] = *(const bf16x8*)(Qp + (size_t)((qb * 2 + wh) * 4 + hs) * 512 + l * 8);

  auto ldK = [&](int t, bf16x8* kr) {
#pragma unroll
    for (int i = 0; i < 8; ++i)
      kr[i] = *(const bf16x8*)(Kp + ((size_t)t * 8 + i) * 512 + l * 8);
  };
  auto ldV = [&](int t, bf16x8* vr) {
#pragma unroll
    for (int i = 0; i < 8; ++i)
      vr[i] = *(const bf16x8*)(Vp + ((size_t)t * 8 + i) * 512 + l * 8);
  };

  const f32x16 z16 = {0,0,0,0, 0,0,0,0, 0,0,0,0, 0,0,0,0};
  f32x16 O0 = z16, O1 = z16;
  float lsum = 0.f;

  auto qk_step = [&](const bf16x8* kr, f32x16& s0, f32x16& s1) {
    s0 = z16; s1 = z16;
    __builtin_amdgcn_s_setprio(1);
#pragma unroll
    for (int hs = 0; hs < 4; ++hs) {
      s0 = __builtin_amdgcn_mfma_f32_32x32x16_bf16(kr[hs * 2 + 0], qf[hs], s0, 0, 0, 0);
      s1 = __builtin_amdgcn_mfma_f32_32x32x16_bf16(kr[hs * 2 + 1], qf[hs], s1, 0, 0, 0);
    }
    __builtin_amdgcn_s_setprio(0);
  };

  auto sm_pv = [&](const bf16x8* vr, f32x16& sc0, f32x16& sc1) {
    float rs = 0.f;
    u32 pk0[8], pk1[8];                          // pk(exp2 sc[2m], exp2 sc[2m+1])
#pragma unroll
    for (int m = 0; m < 8; ++m) {
      float a0 = exp2f(sc0[2 * m]), a1 = exp2f(sc0[2 * m + 1]);
      float c0 = exp2f(sc1[2 * m]), c1 = exp2f(sc1[2 * m + 1]);
      rs += (a0 + a1) + (c0 + c1);
      bf16x2 pA; pA[0] = (__bf16)a0; pA[1] = (__bf16)a1;
      bf16x2 pC; pC[0] = (__bf16)c0; pC[1] = (__bf16)c1;
      pk0[m] = __builtin_bit_cast(u32, pA);
      pk1[m] = __builtin_bit_cast(u32, pC);
    }
    rs += __shfl_xor(rs, 32);
    lsum += rs;
    // direction-proof half exchange (R7): pb[ks] elem j = P[16ks+8hi+j][lq]
    auto xchg = [&](u32 X, u32 Y, u32& wlo, u32& whi) {
      u32 s1v = hiB ? X : Y;
      u32 r = (u32)__shfl_xor((int)s1v, 32);
      wlo = hiB ? r : X;
      whi = hiB ? Y : r;
    };
    bf16x8 pb[4];
    {
      u32 w0, w1, w2, w3;
      xchg(pk0[0], pk0[2], w0, w2);
      xchg(pk0[1], pk0[3], w1, w3);
      u32x4 pw = {w0, w1, w2, w3};
      pb[0] = __builtin_bit_cast(bf16x8, pw);
      xchg(pk0[4], pk0[6], w0, w2);
      xchg(pk0[5], pk0[7], w1, w3);
      u32x4 pw1 = {w0, w1, w2, w3};
      pb[1] = __builtin_bit_cast(bf16x8, pw1);
      xchg(pk1[0], pk1[2], w0, w2);
      xchg(pk1[1], pk1[3], w1, w3);
      u32x4 pw2 = {w0, w1, w2, w3};
      pb[2] = __builtin_bit_cast(bf16x8, pw2);
      xchg(pk1[4], pk1[6], w0, w2);
      xchg(pk1[5], pk1[7], w1, w3);
      u32x4 pw3 = {w0, w1, w2, w3};
      pb[3] = __builtin_bit_cast(bf16x8, pw3);
    }
    __builtin_amdgcn_s_setprio(1);
#pragma unroll
    for (int ks = 0; ks < 4; ++ks) {
      O0 = __builtin_amdgcn_mfma_f32_32x32x16_bf16(vr[ks * 2 + 0], pb[ks], O0, 0, 0, 0);
      O1 = __builtin_amdgcn_mfma_f32_32x32x16_bf16(vr[ks * 2 + 1], pb[ks], O1, 0, 0, 0);
    }
    __builtin_amdgcn_s_setprio(0);
  };

  bf16x8 kA[8], kB[8], vA[8], vB[8];
  f32x16 scX0, scX1;
  const int t0 = ws * 16;               // this wave's k-tile range: [t0, t0+16)
  ldK(t0, kA);
  ldV(t0, vA);
#pragma unroll 1
  for (int dt = 0; dt < 8; ++dt) {
    int t = t0 + dt * 2;
    {   // even sub-iter: consume kA/vA, prefetch t+1 into kB/vB
      ldK(t + 1, kB);
      ldV(t + 1, vB);
      qk_step(kA, scX0, scX1);
      sm_pv(vA, scX0, scX1);
    }
    {   // odd sub-iter: consume kB/vB, prefetch t+2 into kA/vA
      if (dt < 7) { ldK(t + 2, kA); ldV(t + 2, vA); }
      qk_step(kB, scX0, scX1);
      sm_pv(vB, scX0, scX1);
    }
  }
  // --- combine the two k-splits (additive: no max tracking) ---
  if (ws == 1) {
#pragma unroll
    for (int i = 0; i < 16; ++i) {
      cmb[wh][l][i] = O0[i];
      cmb[wh][l][16 + i] = O1[i];
    }
    cmb[wh][l][32] = lsum;
  }
  __syncthreads();
  if (ws == 0) {
#pragma unroll
    for (int i = 0; i < 16; ++i) {
      O0[i] += cmb[wh][l][i];
      O1[i] += cmb[wh][l][16 + i];
    }
    lsum += cmb[wh][l][32];
    float inv = 1.0f / lsum;
    const int q0 = qb * 64 + wh * 32;
    const size_t rowoff = ((size_t)(b * 2048 + q0 + lq)) * 1024 + h * 64;
#pragma unroll
    for (int g = 0; g < 4; ++g) {               // hd = 8g + 4hi + rr (+32 for O1)
      u16x4 oa, ob;
#pragma unroll
      for (int rr = 0; rr < 4; ++rr) {
        oa[rr] = f2bf(O0[4 * g + rr] * inv);
        ob[rr] = f2bf(O1[4 * g + rr] * inv);
      }
      *(u16x4*)(ctx + rowoff + 8 * g + 4 * hi) = oa;
      *(u16x4*)(ctx + rowoff + 32 + 8 * g + 4 * hi) = ob;
    }
  }
}

// ---------------------------------------------------------------- launch
extern "C" void kernel_launch(void* const* d_in, const int* in_sizes, int n_in,
                              void* d_out, int out_size, void* d_ws, size_t ws_size,
                              hipStream_t stream) {
  (void)in_sizes; (void)n_in; (void)out_size; (void)ws_size;
  const float* x  = (const float*)d_in[0];
  const float* Wq = (const float*)d_in[1];
  const float* bq = (const float*)d_in[2];
  const float* Wk = (const float*)d_in[3];
  const float* bk = (const float*)d_in[4];
  const float* Wv = (const float*)d_in[5];
  const float* bv = (const float*)d_in[6];
  const float* Wo = (const float*)d_in[7];
  const float* bo = (const float*)d_in[8];
  const float* gq = (const float*)d_in[9];
  const float* gk = (const float*)d_in[10];
  const float* fc = (const float*)d_in[11];
  const float* fs = (const float*)d_in[12];
  float* out = (float*)d_out;
  char* ws = (char*)d_ws;
  u16*  xb  = (u16*)(ws + 0);           //  8 MB  x bf16 [4096][1024]
  u16*  wqb = (u16*)(ws + 8388608);     //  2 MB each, contiguous x4
  u16*  wkb = (u16*)(ws + 10485760);
  u16*  wvb = (u16*)(ws + 12582912);
  u16*  wob = (u16*)(ws + 14680064);
  u16*  Qfb = (u16*)(ws + 16777216);    //  8 MB bf16 pre-norm q rows
  u16*  Kfb = (u16*)(ws + 25165824);    //  8 MB pre-norm k rows
  u16*  Qfr = (u16*)(ws + 33554432);    //  8 MB Q fragment-major
  u16*  Kfr = (u16*)(ws + 41943040);    //  8 MB K fragment-major
  u16*  Vfr = (u16*)(ws + 50331648);    //  8 MB V fragment-major
  u16*  ctx = (u16*)(ws + 58720256);    //  8 MB bf16 [B,S,D]

  f2b_kernel<<<4096, 256, 0, stream>>>(x, xb, 1048576);
  f2bw_kernel<<<dim3(1024, 4), 256, 0, stream>>>(Wq, Wk, Wv, Wo, wqb);
  qkv_gemm<<<dim3(32, 8, 3), 256, 0, stream>>>(xb, wqb, wkb, wvb, bq, bk, bv, Qfb, Kfb, Vfr);
  rmsrope<<<dim3(4096, 2), 256, 0, stream>>>(Qfb, Kfb, gq, gk, fc, fs, Qfr, Kfr);
  attn_kernel<<<1024, 256, 0, stream>>>(Qfr, Kfr, Vfr, ctx);
  proj_gemm<<<dim3(32, 8), 256, 0, stream>>>(ctx, wob, bo, out);
}

// Round 13
// 168.158 us; speedup vs baseline: 1.9759x; 1.9759x over previous
//
#include <hip/hip_runtime.h>

typedef unsigned short u16;
typedef unsigned int u32;
typedef u16 u16x4 __attribute__((ext_vector_type(4)));
typedef u16 u16x8 __attribute__((ext_vector_type(8)));
typedef u32 u32x4 __attribute__((ext_vector_type(4)));
typedef float f32x4 __attribute__((ext_vector_type(4)));
typedef float f32x16 __attribute__((ext_vector_type(16)));
typedef __bf16 bf16x2 __attribute__((ext_vector_type(2)));
typedef __bf16 bf16x8 __attribute__((ext_vector_type(8)));

#define GLOAD16(gp, lp)                                             \
  __builtin_amdgcn_global_load_lds(                                 \
      (const __attribute__((address_space(1))) void*)(gp),          \
      (__attribute__((address_space(3))) void*)(lp), 16, 0, 0)

__device__ __forceinline__ u16 f2bf(float f) {
  unsigned int u = __builtin_bit_cast(unsigned int, f);
  u += 0x7FFFu + ((u >> 16) & 1u);
  return (u16)(u >> 16);
}
__device__ __forceinline__ float bf2f(u16 h) {
  return __builtin_bit_cast(float, (u32)h << 16);
}

// ---------------------------------------------------------------- f32 -> bf16
__global__ __launch_bounds__(256) void f2b_kernel(const float* __restrict__ in,
                                                  u16* __restrict__ out, int n4) {
  int i = blockIdx.x * 256 + threadIdx.x;
  if (i < n4) {
    f32x4 v = *(const f32x4*)(in + (size_t)i * 4);
    u16x4 o;
    o[0] = f2bf(v[0]); o[1] = f2bf(v[1]); o[2] = f2bf(v[2]); o[3] = f2bf(v[3]);
    *(u16x4*)(out + (size_t)i * 4) = o;
  }
}

// all 4 weight matrices in one launch; dst regions contiguous (1M elems each)
__global__ __launch_bounds__(256) void f2bw_kernel(const float* __restrict__ s0,
    const float* __restrict__ s1, const float* __restrict__ s2,
    const float* __restrict__ s3, u16* __restrict__ dst) {
  const int y = blockIdx.y;
  const float* s = (y == 0) ? s0 : ((y == 1) ? s1 : ((y == 2) ? s2 : s3));
  int i = blockIdx.x * 256 + threadIdx.x;
  f32x4 v = *(const f32x4*)(s + (size_t)i * 4);
  u16x4 o;
  o[0] = f2bf(v[0]); o[1] = f2bf(v[1]); o[2] = f2bf(v[2]); o[3] = f2bf(v[3]);
  *(u16x4*)(dst + (size_t)y * 1048576 + (size_t)i * 4) = o;
}

// --------------------------------------------- NT GEMM core: C = A * W^T
// 128x128 tile, BK=32, 256 thr (4 waves). 3-buffer counted-vmcnt pipeline.
__device__ __forceinline__ void gemm_core(const u16* __restrict__ A,
                                          const u16* __restrict__ W,
                                          int bm0, int bn0,
                                          u16* ldsA, u16* ldsB,
                                          f32x4 acc[4][4]) {
  const int tid = threadIdx.x;
  const int l = tid & 63;
  const int lr = l & 15, lk = l >> 4;
  const int w = tid >> 6;
  const int wr = w >> 1, wc = w & 1;
  const int srow = tid >> 2, sko = (tid & 3) << 3;
  auto stage = [&](int kt, int buf) {  // 4 VMEM loads per thread
#pragma unroll
    for (int it = 0; it < 2; ++it) {
      int row = it * 64 + srow;
      GLOAD16(A + (size_t)(bm0 + row) * 1024 + kt * 32 + sko,
              ldsA + buf * 4096 + (it * 256 + tid) * 8);
      GLOAD16(W + (size_t)(bn0 + row) * 1024 + kt * 32 + sko,
              ldsB + buf * 4096 + (it * 256 + tid) * 8);
    }
  };
  stage(0, 0);
  stage(1, 1);
  int cur = 0, nx2 = 2;
  for (int kt = 0; kt < 32; ++kt) {
    if (kt < 31) asm volatile("s_waitcnt vmcnt(4)" ::: "memory");
    else         asm volatile("s_waitcnt vmcnt(0)" ::: "memory");
    __builtin_amdgcn_s_barrier();
    __builtin_amdgcn_sched_barrier(0);
    if (kt + 2 < 32) stage(kt + 2, nx2);
    const u16* lA = ldsA + cur * 4096;
    const u16* lB = ldsB + cur * 4096;
    bf16x8 af[4], bfr[4];
#pragma unroll
    for (int m = 0; m < 4; ++m)
      af[m] = *(const bf16x8*)(lA + (wr * 64 + m * 16 + lr) * 32 + lk * 8);
#pragma unroll
    for (int n = 0; n < 4; ++n)
      bfr[n] = *(const bf16x8*)(lB + (wc * 64 + n * 16 + lr) * 32 + lk * 8);
#pragma unroll
    for (int m = 0; m < 4; ++m)
#pragma unroll
      for (int n = 0; n < 4; ++n)
        acc[m][n] = __builtin_amdgcn_mfma_f32_16x16x32_bf16(af[m], bfr[n], acc[m][n], 0, 0, 0);
    cur = (cur == 2) ? 0 : cur + 1;
    nx2 = (nx2 == 2) ? 0 : nx2 + 1;
  }
}

// --------------------------------------------- fused QKV projection
// z=0: Q -> Qb rows; z=1: K -> Kb rows; z=2: V -> V-frag [bh][t][ks][half][lane][8]
__global__ __launch_bounds__(256) void qkv_gemm(const u16* __restrict__ xb,
    const u16* __restrict__ wq, const u16* __restrict__ wk, const u16* __restrict__ wv,
    const float* __restrict__ bq, const float* __restrict__ bk, const float* __restrict__ bv,
    u16* __restrict__ Qb, u16* __restrict__ Kb, u16* __restrict__ Vf) {
  __shared__ u16 ldsA[3 * 4096];
  __shared__ u16 ldsB[3 * 4096];
  const int z = blockIdx.z;
  const u16* W = (z == 0) ? wq : ((z == 1) ? wk : wv);
  const float* bias = (z == 0) ? bq : ((z == 1) ? bk : bv);
  const int bm0 = blockIdx.x * 128, bn0 = blockIdx.y * 128;
  const f32x4 zf = {0.f, 0.f, 0.f, 0.f};
  f32x4 acc[4][4];
#pragma unroll
  for (int m = 0; m < 4; ++m)
#pragma unroll
    for (int n = 0; n < 4; ++n) acc[m][n] = zf;
  gemm_core(xb, W, bm0, bn0, ldsA, ldsB, acc);
  const int tid = threadIdx.x, l = tid & 63, lr = l & 15, lk = l >> 4;
  const int w = tid >> 6, wr = w >> 1, wc = w & 1;
  float bcol[4];
#pragma unroll
  for (int n = 0; n < 4; ++n) bcol[n] = bias[bn0 + wc * 64 + n * 16 + lr];
  if (z < 2) {
    u16* outp = z ? Kb : Qb;
#pragma unroll
    for (int m = 0; m < 4; ++m)
#pragma unroll
      for (int n = 0; n < 4; ++n)
#pragma unroll
        for (int r = 0; r < 4; ++r) {
          int row = bm0 + wr * 64 + m * 16 + lk * 4 + r;
          int col = bn0 + wc * 64 + n * 16 + lr;
          outp[(size_t)row * 1024 + col] = f2bf(acc[m][n][r] + bcol[n]);
        }
  } else {
    // V-frag: element (hd, key): t=key>>6, kin=key&63, ks=kin>>4, hi=(kin>>3)&1,
    // j=kin&7, vhalf=hd>>5, lq=hd&31.
#pragma unroll
    for (int m = 0; m < 4; ++m)
#pragma unroll
      for (int n = 0; n < 4; ++n) {
        int row = bm0 + wr * 64 + m * 16 + lk * 4;   // key base (r = 0..3)
        int col = bn0 + wc * 64 + n * 16 + lr;
        int b = row >> 11, sf = row & 2047, hh = col >> 6, hd = col & 63;
        int t = sf >> 6, kin = sf & 63;
        int ks = kin >> 4, hiv = (kin >> 3) & 1, j0 = kin & 7;
        int vhalf = hd >> 5, lq = hd & 31;
        u16x4 o;
#pragma unroll
        for (int r = 0; r < 4; ++r) o[r] = f2bf(acc[m][n][r] + bcol[n]);
        size_t addr = (size_t)(b * 16 + hh) * 131072 +
                      (size_t)(((t * 4 + ks) * 2 + vhalf)) * 512 +
                      ((hiv << 5) + lq) * 8 + j0;
        *(u16x4*)(Vf + addr) = o;
      }
  }
}

// --------------------------------------------- output projection
__global__ __launch_bounds__(256) void proj_gemm(const u16* __restrict__ ctx,
    const u16* __restrict__ wo, const float* __restrict__ bo, float* __restrict__ out) {
  __shared__ u16 ldsA[3 * 4096];
  __shared__ u16 ldsB[3 * 4096];
  const int bm0 = blockIdx.x * 128, bn0 = blockIdx.y * 128;
  const f32x4 zf = {0.f, 0.f, 0.f, 0.f};
  f32x4 acc[4][4];
#pragma unroll
  for (int m = 0; m < 4; ++m)
#pragma unroll
    for (int n = 0; n < 4; ++n) acc[m][n] = zf;
  gemm_core(ctx, wo, bm0, bn0, ldsA, ldsB, acc);
  const int tid = threadIdx.x, l = tid & 63, lr = l & 15, lk = l >> 4;
  const int w = tid >> 6, wr = w >> 1, wc = w & 1;
  float bcol[4];
#pragma unroll
  for (int n = 0; n < 4; ++n) bcol[n] = bo[bn0 + wc * 64 + n * 16 + lr];
#pragma unroll
  for (int m = 0; m < 4; ++m)
#pragma unroll
    for (int n = 0; n < 4; ++n)
#pragma unroll
      for (int r = 0; r < 4; ++r) {
        int row = bm0 + wr * 64 + m * 16 + lk * 4 + r;
        int col = bn0 + wc * 64 + n * 16 + lr;
        out[(size_t)row * 1024 + col] = acc[m][n][r] + bcol[n];
      }
}

// --------------------------------------------- RMSNorm + RoPE -> fragment layouts
// which==0 (q): fold 0.125*log2(e); Q-frag [bh][q>>5][hs][lane][8]
// which==1 (k): K-frag [bh][t][hs][khalf][lane][8]
__global__ __launch_bounds__(256) void rmsrope(const u16* __restrict__ Qb,
    const u16* __restrict__ Kb, const float* __restrict__ gq, const float* __restrict__ gk,
    const float* __restrict__ fc, const float* __restrict__ fs,
    u16* __restrict__ Qf, u16* __restrict__ Kf) {
  const int row = blockIdx.x;
  const int which = blockIdx.y;
  const u16* src = (which ? Kb : Qb) + (size_t)row * 1024;
  const float* g = which ? gk : gq;
  const int t = threadIdx.x;
  u16x4 raw = *(const u16x4*)(src + t * 4);
  float v0 = bf2f(raw[0]), v1 = bf2f(raw[1]), v2 = bf2f(raw[2]), v3 = bf2f(raw[3]);
  float ss = v0 * v0 + v1 * v1 + v2 * v2 + v3 * v3;
#pragma unroll
  for (int mm = 1; mm < 64; mm <<= 1) ss += __shfl_xor(ss, mm);
  __shared__ float red[4];
  if ((t & 63) == 0) red[t >> 6] = ss;
  __syncthreads();
  float rstd = rsqrtf((red[0] + red[1] + red[2] + red[3]) * (1.0f / 1024.0f) + 1e-6f);
  if (!which) rstd *= 0.18033688011112042f;   // 0.125 * log2(e) folded into q
  int d = t * 4, hh = d >> 6, dh = d & 63, p = dh >> 1;
  int s = row & 2047, b = row >> 11;
  float c0 = fc[(s << 5) + p], s0 = fs[(s << 5) + p];
  float c1 = fc[(s << 5) + p + 1], s1 = fs[(s << 5) + p + 1];
  float x0 = v0 * rstd * g[d];
  float x1 = v1 * rstd * g[d + 1];
  float x2 = v2 * rstd * g[d + 2];
  float x3 = v3 * rstd * g[d + 3];
  u16x4 o;
  o[0] = f2bf(x0 * c0 - x1 * s0);
  o[1] = f2bf(x0 * s0 + x1 * c0);
  o[2] = f2bf(x2 * c1 - x3 * s1);
  o[3] = f2bf(x2 * s1 + x3 * c1);
  const size_t base = (size_t)(b * 16 + hh) * 131072;
  const int hs = dh >> 4, hi = (dh >> 3) & 1, j0 = dh & 7;
  size_t addr;
  if (!which) {
    addr = base + (size_t)((s >> 5) * 4 + hs) * 512 + ((hi << 5) + (s & 31)) * 8 + j0;
  } else {
    addr = base + (size_t)(((s >> 6) * 4 + hs) * 2 + ((s >> 5) & 1)) * 512 +
           ((hi << 5) + (s & 31)) * 8 + j0;
  }
  *(u16x4*)((which ? Kf : Qf) + addr) = o;
}

// --------------------------------------------- flash attention (non-causal)
// 1024 blocks x 256 thr (4 waves). Each block owns 64 q-rows; waves 0,1 =
// q-halves x k-tiles 0..15, waves 2,3 = q-halves x k-tiles 16..31. Max-free
// softmax -> additive combine via one LDS exchange. NO launch_bounds
// min-waves hint: R11/R12 showed it makes the allocator spill (~64 VGPR +
// 800 MB scratch). Natural allocation ~110 VGPR already permits 4 waves/SIMD;
// grid 1024 = 4 blocks/CU supplies them.
__global__ __launch_bounds__(256) void attn_kernel(const u16* __restrict__ Qf,
    const u16* __restrict__ Kf, const u16* __restrict__ Vf, u16* __restrict__ ctx) {
  __shared__ float cmb[2][64][33];   // combine: O0(16)+O1(16)+lsum
  const int tid = threadIdx.x;
  const int w = tid >> 6, l = tid & 63;
  const int wh = w & 1, ws = w >> 1;          // q-half, k-split
  const int lq = l & 31, hi = l >> 5;
  const bool hiB = (hi != 0);
  // 1024 = 8 (xcd) x ... : qb = (id>>3)&31 (64-row block), hb = (id&7)|((id>>8)<<3)
  const int id = blockIdx.x;
  const int qb = (id >> 3) & 31;
  const int hb = (id & 7) | ((id >> 8) << 3);
  const int h = hb & 15, b = hb >> 4;
  const int bh = b * 16 + h;
  const u16* Qp = Qf + (size_t)bh * 131072;
  const u16* Kp = Kf + (size_t)bh * 131072;
  const u16* Vp = Vf + (size_t)bh * 131072;
  bf16x8 qf[4];
#pragma unroll
  for (int hs = 0; hs < 4; ++hs)
    qf[hs] = *(const bf16x8*)(Qp + (size_t)((qb * 2 + wh) * 4 + hs) * 512 + l * 8);

  auto ldK = [&](int t, bf16x8* kr) {
#pragma unroll
    for (int i = 0; i < 8; ++i)
      kr[i] = *(const bf16x8*)(Kp + ((size_t)t * 8 + i) * 512 + l * 8);
  };
  auto ldV = [&](int t, bf16x8* vr) {
#pragma unroll
    for (int i = 0; i < 8; ++i)
      vr[i] = *(const bf16x8*)(Vp + ((size_t)t * 8 + i) * 512 + l * 8);
  };

  const f32x16 z16 = {0,0,0,0, 0,0,0,0, 0,0,0,0, 0,0,0,0};
  f32x16 O0 = z16, O1 = z16;
  float lsum = 0.f;

  auto qk_step = [&](const bf16x8* kr, f32x16& s0, f32x16& s1) {
    s0 = z16; s1 = z16;
    __builtin_amdgcn_s_setprio(1);
#pragma unroll
    for (int hs = 0; hs < 4; ++hs) {
      s0 = __builtin_amdgcn_mfma_f32_32x32x16_bf16(kr[hs * 2 + 0], qf[hs], s0, 0, 0, 0);
      s1 = __builtin_amdgcn_mfma_f32_32x32x16_bf16(kr[hs * 2 + 1], qf[hs], s1, 0, 0, 0);
    }
    __builtin_amdgcn_s_setprio(0);
  };

  auto sm_pv = [&](const bf16x8* vr, f32x16& sc0, f32x16& sc1) {
    float rs = 0.f;
    u32 pk0[8], pk1[8];                          // pk(exp2 sc[2m], exp2 sc[2m+1])
#pragma unroll
    for (int m = 0; m < 8; ++m) {
      float a0 = exp2f(sc0[2 * m]), a1 = exp2f(sc0[2 * m + 1]);
      float c0 = exp2f(sc1[2 * m]), c1 = exp2f(sc1[2 * m + 1]);
      rs += (a0 + a1) + (c0 + c1);
      bf16x2 pA; pA[0] = (__bf16)a0; pA[1] = (__bf16)a1;
      bf16x2 pC; pC[0] = (__bf16)c0; pC[1] = (__bf16)c1;
      pk0[m] = __builtin_bit_cast(u32, pA);
      pk1[m] = __builtin_bit_cast(u32, pC);
    }
    rs += __shfl_xor(rs, 32);
    lsum += rs;
    // direction-proof half exchange (R7): pb[ks] elem j = P[16ks+8hi+j][lq]
    auto xchg = [&](u32 X, u32 Y, u32& wlo, u32& whi) {
      u32 s1v = hiB ? X : Y;
      u32 r = (u32)__shfl_xor((int)s1v, 32);
      wlo = hiB ? r : X;
      whi = hiB ? Y : r;
    };
    bf16x8 pb[4];
    {
      u32 w0, w1, w2, w3;
      xchg(pk0[0], pk0[2], w0, w2);
      xchg(pk0[1], pk0[3], w1, w3);
      u32x4 pw = {w0, w1, w2, w3};
      pb[0] = __builtin_bit_cast(bf16x8, pw);
      xchg(pk0[4], pk0[6], w0, w2);
      xchg(pk0[5], pk0[7], w1, w3);
      u32x4 pw1 = {w0, w1, w2, w3};
      pb[1] = __builtin_bit_cast(bf16x8, pw1);
      xchg(pk1[0], pk1[2], w0, w2);
      xchg(pk1[1], pk1[3], w1, w3);
      u32x4 pw2 = {w0, w1, w2, w3};
      pb[2] = __builtin_bit_cast(bf16x8, pw2);
      xchg(pk1[4], pk1[6], w0, w2);
      xchg(pk1[5], pk1[7], w1, w3);
      u32x4 pw3 = {w0, w1, w2, w3};
      pb[3] = __builtin_bit_cast(bf16x8, pw3);
    }
    __builtin_amdgcn_s_setprio(1);
#pragma unroll
    for (int ks = 0; ks < 4; ++ks) {
      O0 = __builtin_amdgcn_mfma_f32_32x32x16_bf16(vr[ks * 2 + 0], pb[ks], O0, 0, 0, 0);
      O1 = __builtin_amdgcn_mfma_f32_32x32x16_bf16(vr[ks * 2 + 1], pb[ks], O1, 0, 0, 0);
    }
    __builtin_amdgcn_s_setprio(0);
  };

  bf16x8 kA[8], kB[8], vA[8], vB[8];
  f32x16 scX0, scX1;
  const int t0 = ws * 16;               // this wave's k-tile range: [t0, t0+16)
  ldK(t0, kA);
  ldV(t0, vA);
#pragma unroll 1
  for (int dt = 0; dt < 8; ++dt) {
    int t = t0 + dt * 2;
    {   // even sub-iter: consume kA/vA, prefetch t+1 into kB/vB
      ldK(t + 1, kB);
      ldV(t + 1, vB);
      qk_step(kA, scX0, scX1);
      sm_pv(vA, scX0, scX1);
    }
    {   // odd sub-iter: consume kB/vB, prefetch t+2 into kA/vA
      if (dt < 7) { ldK(t + 2, kA); ldV(t + 2, vA); }
      qk_step(kB, scX0, scX1);
      sm_pv(vB, scX0, scX1);
    }
  }
  // --- combine the two k-splits (additive: no max tracking) ---
  if (ws == 1) {
#pragma unroll
    for (int i = 0; i < 16; ++i) {
      cmb[wh][l][i] = O0[i];
      cmb[wh][l][16 + i] = O1[i];
    }
    cmb[wh][l][32] = lsum;
  }
  __syncthreads();
  if (ws == 0) {
#pragma unroll
    for (int i = 0; i < 16; ++i) {
      O0[i] += cmb[wh][l][i];
      O1[i] += cmb[wh][l][16 + i];
    }
    lsum += cmb[wh][l][32];
    float inv = 1.0f / lsum;
    const int q0 = qb * 64 + wh * 32;
    const size_t rowoff = ((size_t)(b * 2048 + q0 + lq)) * 1024 + h * 64;
#pragma unroll
    for (int g = 0; g < 4; ++g) {               // hd = 8g + 4hi + rr (+32 for O1)
      u16x4 oa, ob;
#pragma unroll
      for (int rr = 0; rr < 4; ++rr) {
        oa[rr] = f2bf(O0[4 * g + rr] * inv);
        ob[rr] = f2bf(O1[4 * g + rr] * inv);
      }
      *(u16x4*)(ctx + rowoff + 8 * g + 4 * hi) = oa;
      *(u16x4*)(ctx + rowoff + 32 + 8 * g + 4 * hi) = ob;
    }
  }
}

// ---------------------------------------------------------------- launch
extern "C" void kernel_launch(void* const* d_in, const int* in_sizes, int n_in,
                              void* d_out, int out_size, void* d_ws, size_t ws_size,
                              hipStream_t stream) {
  (void)in_sizes; (void)n_in; (void)out_size; (void)ws_size;
  const float* x  = (const float*)d_in[0];
  const float* Wq = (const float*)d_in[1];
  const float* bq = (const float*)d_in[2];
  const float* Wk = (const float*)d_in[3];
  const float* bk = (const float*)d_in[4];
  const float* Wv = (const float*)d_in[5];
  const float* bv = (const float*)d_in[6];
  const float* Wo = (const float*)d_in[7];
  const float* bo = (const float*)d_in[8];
  const float* gq = (const float*)d_in[9];
  const float* gk = (const float*)d_in[10];
  const float* fc = (const float*)d_in[11];
  const float* fs = (const float*)d_in[12];
  float* out = (float*)d_out;
  char* ws = (char*)d_ws;
  u16*  xb  = (u16*)(ws + 0);           //  8 MB  x bf16 [4096][1024]
  u16*  wqb = (u16*)(ws + 8388608);     //  2 MB each, contiguous x4
  u16*  wkb = (u16*)(ws + 10485760);
  u16*  wvb = (u16*)(ws + 12582912);
  u16*  wob = (u16*)(ws + 14680064);
  u16*  Qfb = (u16*)(ws + 16777216);    //  8 MB bf16 pre-norm q rows
  u16*  Kfb = (u16*)(ws + 25165824);    //  8 MB pre-norm k rows
  u16*  Qfr = (u16*)(ws + 33554432);    //  8 MB Q fragment-major
  u16*  Kfr = (u16*)(ws + 41943040);    //  8 MB K fragment-major
  u16*  Vfr = (u16*)(ws + 50331648);    //  8 MB V fragment-major
  u16*  ctx = (u16*)(ws + 58720256);    //  8 MB bf16 [B,S,D]

  f2b_kernel<<<4096, 256, 0, stream>>>(x, xb, 1048576);
  f2bw_kernel<<<dim3(1024, 4), 256, 0, stream>>>(Wq, Wk, Wv, Wo, wqb);
  qkv_gemm<<<dim3(32, 8, 3), 256, 0, stream>>>(xb, wqb, wkb, wvb, bq, bk, bv, Qfb, Kfb, Vfr);
  rmsrope<<<dim3(4096, 2), 256, 0, stream>>>(Qfb, Kfb, gq, gk, fc, fs, Qfr, Kfr);
  attn_kernel<<<1024, 256, 0, stream>>>(Qfr, Kfr, Vfr, ctx);
  proj_gemm<<<dim3(32, 8), 256, 0, stream>>>(ctx, wob, bo, out);
}

// Round 14
// 149.998 us; speedup vs baseline: 2.2151x; 1.1211x over previous
//
#include <hip/hip_runtime.h>

typedef unsigned short u16;
typedef unsigned int u32;
typedef u16 u16x4 __attribute__((ext_vector_type(4)));
typedef u16 u16x8 __attribute__((ext_vector_type(8)));
typedef u32 u32x4 __attribute__((ext_vector_type(4)));
typedef float f32x4 __attribute__((ext_vector_type(4)));
typedef float f32x16 __attribute__((ext_vector_type(16)));
typedef __bf16 bf16x2 __attribute__((ext_vector_type(2)));
typedef __bf16 bf16x8 __attribute__((ext_vector_type(8)));

#define GLOAD16(gp, lp)                                             \
  __builtin_amdgcn_global_load_lds(                                 \
      (const __attribute__((address_space(1))) void*)(gp),          \
      (__attribute__((address_space(3))) void*)(lp), 16, 0, 0)

__device__ __forceinline__ u16 f2bf(float f) {
  unsigned int u = __builtin_bit_cast(unsigned int, f);
  u += 0x7FFFu + ((u >> 16) & 1u);
  return (u16)(u >> 16);
}
__device__ __forceinline__ float bf2f(u16 h) {
  return __builtin_bit_cast(float, (u32)h << 16);
}

// ---------------------------------------------------------------- f32 -> bf16
__global__ __launch_bounds__(256) void f2b_kernel(const float* __restrict__ in,
                                                  u16* __restrict__ out, int n4) {
  int i = blockIdx.x * 256 + threadIdx.x;
  if (i < n4) {
    f32x4 v = *(const f32x4*)(in + (size_t)i * 4);
    u16x4 o;
    o[0] = f2bf(v[0]); o[1] = f2bf(v[1]); o[2] = f2bf(v[2]); o[3] = f2bf(v[3]);
    *(u16x4*)(out + (size_t)i * 4) = o;
  }
}

// all 4 weight matrices in one launch; dst regions contiguous (1M elems each)
__global__ __launch_bounds__(256) void f2bw_kernel(const float* __restrict__ s0,
    const float* __restrict__ s1, const float* __restrict__ s2,
    const float* __restrict__ s3, u16* __restrict__ dst) {
  const int y = blockIdx.y;
  const float* s = (y == 0) ? s0 : ((y == 1) ? s1 : ((y == 2) ? s2 : s3));
  int i = blockIdx.x * 256 + threadIdx.x;
  f32x4 v = *(const f32x4*)(s + (size_t)i * 4);
  u16x4 o;
  o[0] = f2bf(v[0]); o[1] = f2bf(v[1]); o[2] = f2bf(v[2]); o[3] = f2bf(v[3]);
  *(u16x4*)(dst + (size_t)y * 1048576 + (size_t)i * 4) = o;
}

// --------------------------------------------- NT GEMM core: C = A * W^T
// 128x128 tile, BK=32, 256 thr (4 waves). 3-buffer counted-vmcnt pipeline.
__device__ __forceinline__ void gemm_core(const u16* __restrict__ A,
                                          const u16* __restrict__ W,
                                          int bm0, int bn0,
                                          u16* ldsA, u16* ldsB,
                                          f32x4 acc[4][4]) {
  const int tid = threadIdx.x;
  const int l = tid & 63;
  const int lr = l & 15, lk = l >> 4;
  const int w = tid >> 6;
  const int wr = w >> 1, wc = w & 1;
  const int srow = tid >> 2, sko = (tid & 3) << 3;
  auto stage = [&](int kt, int buf) {  // 4 VMEM loads per thread
#pragma unroll
    for (int it = 0; it < 2; ++it) {
      int row = it * 64 + srow;
      GLOAD16(A + (size_t)(bm0 + row) * 1024 + kt * 32 + sko,
              ldsA + buf * 4096 + (it * 256 + tid) * 8);
      GLOAD16(W + (size_t)(bn0 + row) * 1024 + kt * 32 + sko,
              ldsB + buf * 4096 + (it * 256 + tid) * 8);
    }
  };
  stage(0, 0);
  stage(1, 1);
  int cur = 0, nx2 = 2;
  for (int kt = 0; kt < 32; ++kt) {
    if (kt < 31) asm volatile("s_waitcnt vmcnt(4)" ::: "memory");
    else         asm volatile("s_waitcnt vmcnt(0)" ::: "memory");
    __builtin_amdgcn_s_barrier();
    __builtin_amdgcn_sched_barrier(0);
    if (kt + 2 < 32) stage(kt + 2, nx2);
    const u16* lA = ldsA + cur * 4096;
    const u16* lB = ldsB + cur * 4096;
    bf16x8 af[4], bfr[4];
#pragma unroll
    for (int m = 0; m < 4; ++m)
      af[m] = *(const bf16x8*)(lA + (wr * 64 + m * 16 + lr) * 32 + lk * 8);
#pragma unroll
    for (int n = 0; n < 4; ++n)
      bfr[n] = *(const bf16x8*)(lB + (wc * 64 + n * 16 + lr) * 32 + lk * 8);
#pragma unroll
    for (int m = 0; m < 4; ++m)
#pragma unroll
      for (int n = 0; n < 4; ++n)
        acc[m][n] = __builtin_amdgcn_mfma_f32_16x16x32_bf16(af[m], bfr[n], acc[m][n], 0, 0, 0);
    cur = (cur == 2) ? 0 : cur + 1;
    nx2 = (nx2 == 2) ? 0 : nx2 + 1;
  }
}

// --------------------------------------------- fused QKV projection
// z=0: Q -> Qb rows; z=1: K -> Kb rows; z=2: V -> V-frag [bh][t][ks][half][lane][8]
__global__ __launch_bounds__(256) void qkv_gemm(const u16* __restrict__ xb,
    const u16* __restrict__ wq, const u16* __restrict__ wk, const u16* __restrict__ wv,
    const float* __restrict__ bq, const float* __restrict__ bk, const float* __restrict__ bv,
    u16* __restrict__ Qb, u16* __restrict__ Kb, u16* __restrict__ Vf) {
  __shared__ u16 ldsA[3 * 4096];
  __shared__ u16 ldsB[3 * 4096];
  const int z = blockIdx.z;
  const u16* W = (z == 0) ? wq : ((z == 1) ? wk : wv);
  const float* bias = (z == 0) ? bq : ((z == 1) ? bk : bv);
  const int bm0 = blockIdx.x * 128, bn0 = blockIdx.y * 128;
  const f32x4 zf = {0.f, 0.f, 0.f, 0.f};
  f32x4 acc[4][4];
#pragma unroll
  for (int m = 0; m < 4; ++m)
#pragma unroll
    for (int n = 0; n < 4; ++n) acc[m][n] = zf;
  gemm_core(xb, W, bm0, bn0, ldsA, ldsB, acc);
  const int tid = threadIdx.x, l = tid & 63, lr = l & 15, lk = l >> 4;
  const int w = tid >> 6, wr = w >> 1, wc = w & 1;
  float bcol[4];
#pragma unroll
  for (int n = 0; n < 4; ++n) bcol[n] = bias[bn0 + wc * 64 + n * 16 + lr];
  if (z < 2) {
    u16* outp = z ? Kb : Qb;
#pragma unroll
    for (int m = 0; m < 4; ++m)
#pragma unroll
      for (int n = 0; n < 4; ++n)
#pragma unroll
        for (int r = 0; r < 4; ++r) {
          int row = bm0 + wr * 64 + m * 16 + lk * 4 + r;
          int col = bn0 + wc * 64 + n * 16 + lr;
          outp[(size_t)row * 1024 + col] = f2bf(acc[m][n][r] + bcol[n]);
        }
  } else {
    // V-frag: element (hd, key): t=key>>6, kin=key&63, ks=kin>>4, hi=(kin>>3)&1,
    // j=kin&7, vhalf=hd>>5, lq=hd&31.
#pragma unroll
    for (int m = 0; m < 4; ++m)
#pragma unroll
      for (int n = 0; n < 4; ++n) {
        int row = bm0 + wr * 64 + m * 16 + lk * 4;   // key base (r = 0..3)
        int col = bn0 + wc * 64 + n * 16 + lr;
        int b = row >> 11, sf = row & 2047, hh = col >> 6, hd = col & 63;
        int t = sf >> 6, kin = sf & 63;
        int ks = kin >> 4, hiv = (kin >> 3) & 1, j0 = kin & 7;
        int vhalf = hd >> 5, lq = hd & 31;
        u16x4 o;
#pragma unroll
        for (int r = 0; r < 4; ++r) o[r] = f2bf(acc[m][n][r] + bcol[n]);
        size_t addr = (size_t)(b * 16 + hh) * 131072 +
                      (size_t)(((t * 4 + ks) * 2 + vhalf)) * 512 +
                      ((hiv << 5) + lq) * 8 + j0;
        *(u16x4*)(Vf + addr) = o;
      }
  }
}

// --------------------------------------------- output projection
__global__ __launch_bounds__(256) void proj_gemm(const u16* __restrict__ ctx,
    const u16* __restrict__ wo, const float* __restrict__ bo, float* __restrict__ out) {
  __shared__ u16 ldsA[3 * 4096];
  __shared__ u16 ldsB[3 * 4096];
  const int bm0 = blockIdx.x * 128, bn0 = blockIdx.y * 128;
  const f32x4 zf = {0.f, 0.f, 0.f, 0.f};
  f32x4 acc[4][4];
#pragma unroll
  for (int m = 0; m < 4; ++m)
#pragma unroll
    for (int n = 0; n < 4; ++n) acc[m][n] = zf;
  gemm_core(ctx, wo, bm0, bn0, ldsA, ldsB, acc);
  const int tid = threadIdx.x, l = tid & 63, lr = l & 15, lk = l >> 4;
  const int w = tid >> 6, wr = w >> 1, wc = w & 1;
  float bcol[4];
#pragma unroll
  for (int n = 0; n < 4; ++n) bcol[n] = bo[bn0 + wc * 64 + n * 16 + lr];
#pragma unroll
  for (int m = 0; m < 4; ++m)
#pragma unroll
    for (int n = 0; n < 4; ++n)
#pragma unroll
      for (int r = 0; r < 4; ++r) {
        int row = bm0 + wr * 64 + m * 16 + lk * 4 + r;
        int col = bn0 + wc * 64 + n * 16 + lr;
        out[(size_t)row * 1024 + col] = acc[m][n][r] + bcol[n];
      }
}

// --------------------------------------------- RMSNorm + RoPE -> fragment layouts
// which==0 (q): fold 0.125*log2(e); Q-frag [bh][q>>5][hs][lane][8]
// which==1 (k): K-frag [bh][t][hs][khalf][lane][8]
__global__ __launch_bounds__(256) void rmsrope(const u16* __restrict__ Qb,
    const u16* __restrict__ Kb, const float* __restrict__ gq, const float* __restrict__ gk,
    const float* __restrict__ fc, const float* __restrict__ fs,
    u16* __restrict__ Qf, u16* __restrict__ Kf) {
  const int row = blockIdx.x;
  const int which = blockIdx.y;
  const u16* src = (which ? Kb : Qb) + (size_t)row * 1024;
  const float* g = which ? gk : gq;
  const int t = threadIdx.x;
  u16x4 raw = *(const u16x4*)(src + t * 4);
  float v0 = bf2f(raw[0]), v1 = bf2f(raw[1]), v2 = bf2f(raw[2]), v3 = bf2f(raw[3]);
  float ss = v0 * v0 + v1 * v1 + v2 * v2 + v3 * v3;
#pragma unroll
  for (int mm = 1; mm < 64; mm <<= 1) ss += __shfl_xor(ss, mm);
  __shared__ float red[4];
  if ((t & 63) == 0) red[t >> 6] = ss;
  __syncthreads();
  float rstd = rsqrtf((red[0] + red[1] + red[2] + red[3]) * (1.0f / 1024.0f) + 1e-6f);
  if (!which) rstd *= 0.18033688011112042f;   // 0.125 * log2(e) folded into q
  int d = t * 4, hh = d >> 6, dh = d & 63, p = dh >> 1;
  int s = row & 2047, b = row >> 11;
  float c0 = fc[(s << 5) + p], s0 = fs[(s << 5) + p];
  float c1 = fc[(s << 5) + p + 1], s1 = fs[(s << 5) + p + 1];
  float x0 = v0 * rstd * g[d];
  float x1 = v1 * rstd * g[d + 1];
  float x2 = v2 * rstd * g[d + 2];
  float x3 = v3 * rstd * g[d + 3];
  u16x4 o;
  o[0] = f2bf(x0 * c0 - x1 * s0);
  o[1] = f2bf(x0 * s0 + x1 * c0);
  o[2] = f2bf(x2 * c1 - x3 * s1);
  o[3] = f2bf(x2 * s1 + x3 * c1);
  const size_t base = (size_t)(b * 16 + hh) * 131072;
  const int hs = dh >> 4, hi = (dh >> 3) & 1, j0 = dh & 7;
  size_t addr;
  if (!which) {
    addr = base + (size_t)((s >> 5) * 4 + hs) * 512 + ((hi << 5) + (s & 31)) * 8 + j0;
  } else {
    addr = base + (size_t)(((s >> 6) * 4 + hs) * 2 + ((s >> 5) & 1)) * 512 +
           ((hi << 5) + (s & 31)) * 8 + j0;
  }
  *(u16x4*)((which ? Kf : Qf) + addr) = o;
}

// --------------------------------------------- flash attention (non-causal)
// 1024 blocks x 256 thr (4 waves). Block owns 64 q-rows; waves 0,1 = q-halves
// x k-tiles 0..15, waves 2,3 = q-halves x k-tiles 16..31. Max-free softmax ->
// additive combine. V is SINGLE-buffered (R13 post-mortem: V dbuf pushed VGPR
// to 140 > 128 -> only 3 blocks/CU + straggler round; dropping it targets
// <=128 VGPR so the 1024-block grid runs as one uniform 4-blocks/CU round).
__global__ __launch_bounds__(256) void attn_kernel(const u16* __restrict__ Qf,
    const u16* __restrict__ Kf, const u16* __restrict__ Vf, u16* __restrict__ ctx) {
  __shared__ float cmb[2][64][33];   // combine: O0(16)+O1(16)+lsum
  const int tid = threadIdx.x;
  const int w = tid >> 6, l = tid & 63;
  const int wh = w & 1, ws = w >> 1;          // q-half, k-split
  const int lq = l & 31, hi = l >> 5;
  const bool hiB = (hi != 0);
  const int id = blockIdx.x;
  const int qb = (id >> 3) & 31;
  const int hb = (id & 7) | ((id >> 8) << 3);
  const int h = hb & 15, b = hb >> 4;
  const int bh = b * 16 + h;
  const u16* Qp = Qf + (size_t)bh * 131072;
  const u16* Kp = Kf + (size_t)bh * 131072;
  const u16* Vp = Vf + (size_t)bh * 131072;
  bf16x8 qf[4];
#pragma unroll
  for (int hs = 0; hs < 4; ++hs)
    qf[hs] = *(const bf16x8*)(Qp + (size_t)((qb * 2 + wh) * 4 + hs) * 512 + l * 8);

  auto ldK = [&](int t, bf16x8* kr) {
#pragma unroll
    for (int i = 0; i < 8; ++i)
      kr[i] = *(const bf16x8*)(Kp + ((size_t)t * 8 + i) * 512 + l * 8);
  };
  auto ldV = [&](int t, bf16x8* vr) {
#pragma unroll
    for (int i = 0; i < 8; ++i)
      vr[i] = *(const bf16x8*)(Vp + ((size_t)t * 8 + i) * 512 + l * 8);
  };

  const f32x16 z16 = {0,0,0,0, 0,0,0,0, 0,0,0,0, 0,0,0,0};
  f32x16 O0 = z16, O1 = z16;
  float lsum = 0.f;

  auto qk_step = [&](const bf16x8* kr, f32x16& s0, f32x16& s1) {
    s0 = z16; s1 = z16;
    __builtin_amdgcn_s_setprio(1);
#pragma unroll
    for (int hs = 0; hs < 4; ++hs) {
      s0 = __builtin_amdgcn_mfma_f32_32x32x16_bf16(kr[hs * 2 + 0], qf[hs], s0, 0, 0, 0);
      s1 = __builtin_amdgcn_mfma_f32_32x32x16_bf16(kr[hs * 2 + 1], qf[hs], s1, 0, 0, 0);
    }
    __builtin_amdgcn_s_setprio(0);
  };

  auto sm_pv = [&](const bf16x8* vr, f32x16& sc0, f32x16& sc1) {
    float rs = 0.f;
    u32 pk0[8], pk1[8];                          // pk(exp2 sc[2m], exp2 sc[2m+1])
#pragma unroll
    for (int m = 0; m < 8; ++m) {
      float a0 = exp2f(sc0[2 * m]), a1 = exp2f(sc0[2 * m + 1]);
      float c0 = exp2f(sc1[2 * m]), c1 = exp2f(sc1[2 * m + 1]);
      rs += (a0 + a1) + (c0 + c1);
      bf16x2 pA; pA[0] = (__bf16)a0; pA[1] = (__bf16)a1;
      bf16x2 pC; pC[0] = (__bf16)c0; pC[1] = (__bf16)c1;
      pk0[m] = __builtin_bit_cast(u32, pA);
      pk1[m] = __builtin_bit_cast(u32, pC);
    }
    rs += __shfl_xor(rs, 32);
    lsum += rs;
    // direction-proof half exchange (R7): pb[ks] elem j = P[16ks+8hi+j][lq]
    auto xchg = [&](u32 X, u32 Y, u32& wlo, u32& whi) {
      u32 s1v = hiB ? X : Y;
      u32 r = (u32)__shfl_xor((int)s1v, 32);
      wlo = hiB ? r : X;
      whi = hiB ? Y : r;
    };
    bf16x8 pb[4];
    {
      u32 w0, w1, w2, w3;
      xchg(pk0[0], pk0[2], w0, w2);
      xchg(pk0[1], pk0[3], w1, w3);
      u32x4 pw = {w0, w1, w2, w3};
      pb[0] = __builtin_bit_cast(bf16x8, pw);
      xchg(pk0[4], pk0[6], w0, w2);
      xchg(pk0[5], pk0[7], w1, w3);
      u32x4 pw1 = {w0, w1, w2, w3};
      pb[1] = __builtin_bit_cast(bf16x8, pw1);
      xchg(pk1[0], pk1[2], w0, w2);
      xchg(pk1[1], pk1[3], w1, w3);
      u32x4 pw2 = {w0, w1, w2, w3};
      pb[2] = __builtin_bit_cast(bf16x8, pw2);
      xchg(pk1[4], pk1[6], w0, w2);
      xchg(pk1[5], pk1[7], w1, w3);
      u32x4 pw3 = {w0, w1, w2, w3};
      pb[3] = __builtin_bit_cast(bf16x8, pw3);
    }
    __builtin_amdgcn_s_setprio(1);
#pragma unroll
    for (int ks = 0; ks < 4; ++ks) {
      O0 = __builtin_amdgcn_mfma_f32_32x32x16_bf16(vr[ks * 2 + 0], pb[ks], O0, 0, 0, 0);
      O1 = __builtin_amdgcn_mfma_f32_32x32x16_bf16(vr[ks * 2 + 1], pb[ks], O1, 0, 0, 0);
    }
    __builtin_amdgcn_s_setprio(0);
  };

  bf16x8 kA[8], kB[8], vV[8];
  f32x16 scX0, scX1;
  const int t0 = ws * 16;               // this wave's k-tile range: [t0, t0+16)
  ldK(t0, kA);
#pragma unroll 1
  for (int dt = 0; dt < 8; ++dt) {
    int t = t0 + dt * 2;
    {   // even sub-iter: consume kA; prefetch K(t+1); V(t) single-buffered,
        // issued before QK so its latency hides under MFMA+exp2
      ldK(t + 1, kB);
      ldV(t, vV);
      qk_step(kA, scX0, scX1);
      sm_pv(vV, scX0, scX1);
    }
    {   // odd sub-iter: consume kB; prefetch K(t+2); V(t+1)
      if (dt < 7) ldK(t + 2, kA);
      ldV(t + 1, vV);
      qk_step(kB, scX0, scX1);
      sm_pv(vV, scX0, scX1);
    }
  }
  // --- combine the two k-splits (additive: no max tracking) ---
  if (ws == 1) {
#pragma unroll
    for (int i = 0; i < 16; ++i) {
      cmb[wh][l][i] = O0[i];
      cmb[wh][l][16 + i] = O1[i];
    }
    cmb[wh][l][32] = lsum;
  }
  __syncthreads();
  if (ws == 0) {
#pragma unroll
    for (int i = 0; i < 16; ++i) {
      O0[i] += cmb[wh][l][i];
      O1[i] += cmb[wh][l][16 + i];
    }
    lsum += cmb[wh][l][32];
    float inv = 1.0f / lsum;
    const int q0 = qb * 64 + wh * 32;
    const size_t rowoff = ((size_t)(b * 2048 + q0 + lq)) * 1024 + h * 64;
#pragma unroll
    for (int g = 0; g < 4; ++g) {               // hd = 8g + 4hi + rr (+32 for O1)
      u16x4 oa, ob;
#pragma unroll
      for (int rr = 0; rr < 4; ++rr) {
        oa[rr] = f2bf(O0[4 * g + rr] * inv);
        ob[rr] = f2bf(O1[4 * g + rr] * inv);
      }
      *(u16x4*)(ctx + rowoff + 8 * g + 4 * hi) = oa;
      *(u16x4*)(ctx + rowoff + 32 + 8 * g + 4 * hi) = ob;
    }
  }
}

// ---------------------------------------------------------------- launch
extern "C" void kernel_launch(void* const* d_in, const int* in_sizes, int n_in,
                              void* d_out, int out_size, void* d_ws, size_t ws_size,
                              hipStream_t stream) {
  (void)in_sizes; (void)n_in; (void)out_size; (void)ws_size;
  const float* x  = (const float*)d_in[0];
  const float* Wq = (const float*)d_in[1];
  const float* bq = (const float*)d_in[2];
  const float* Wk = (const float*)d_in[3];
  const float* bk = (const float*)d_in[4];
  const float* Wv = (const float*)d_in[5];
  const float* bv = (const float*)d_in[6];
  const float* Wo = (const float*)d_in[7];
  const float* bo = (const float*)d_in[8];
  const float* gq = (const float*)d_in[9];
  const float* gk = (const float*)d_in[10];
  const float* fc = (const float*)d_in[11];
  const float* fs = (const float*)d_in[12];
  float* out = (float*)d_out;
  char* ws = (char*)d_ws;
  u16*  xb  = (u16*)(ws + 0);           //  8 MB  x bf16 [4096][1024]
  u16*  wqb = (u16*)(ws + 8388608);     //  2 MB each, contiguous x4
  u16*  wkb = (u16*)(ws + 10485760);
  u16*  wvb = (u16*)(ws + 12582912);
  u16*  wob = (u16*)(ws + 14680064);
  u16*  Qfb = (u16*)(ws + 16777216);    //  8 MB bf16 pre-norm q rows
  u16*  Kfb = (u16*)(ws + 25165824);    //  8 MB pre-norm k rows
  u16*  Qfr = (u16*)(ws + 33554432);    //  8 MB Q fragment-major
  u16*  Kfr = (u16*)(ws + 41943040);    //  8 MB K fragment-major
  u16*  Vfr = (u16*)(ws + 50331648);    //  8 MB V fragment-major
  u16*  ctx = (u16*)(ws + 58720256);    //  8 MB bf16 [B,S,D]

  f2b_kernel<<<4096, 256, 0, stream>>>(x, xb, 1048576);
  f2bw_kernel<<<dim3(1024, 4), 256, 0, stream>>>(Wq, Wk, Wv, Wo, wqb);
  qkv_gemm<<<dim3(32, 8, 3), 256, 0, stream>>>(xb, wqb, wkb, wvb, bq, bk, bv, Qfb, Kfb, Vfr);
  rmsrope<<<dim3(4096, 2), 256, 0, stream>>>(Qfb, Kfb, gq, gk, fc, fs, Qfr, Kfr);
  attn_kernel<<<1024, 256, 0, stream>>>(Qfr, Kfr, Vfr, ctx);
  proj_gemm<<<dim3(32, 8), 256, 0, stream>>>(ctx, wob, bo, out);
}

// Round 15
// 143.497 us; speedup vs baseline: 2.3155x; 1.0453x over previous
//
#include <hip/hip_runtime.h>

typedef unsigned short u16;
typedef unsigned int u32;
typedef u16 u16x4 __attribute__((ext_vector_type(4)));
typedef u16 u16x8 __attribute__((ext_vector_type(8)));
typedef u32 u32x4 __attribute__((ext_vector_type(4)));
typedef float f32x4 __attribute__((ext_vector_type(4)));
typedef float f32x16 __attribute__((ext_vector_type(16)));
typedef __bf16 bf16x2 __attribute__((ext_vector_type(2)));
typedef __bf16 bf16x8 __attribute__((ext_vector_type(8)));

#define GLOAD16(gp, lp)                                             \
  __builtin_amdgcn_global_load_lds(                                 \
      (const __attribute__((address_space(1))) void*)(gp),          \
      (__attribute__((address_space(3))) void*)(lp), 16, 0, 0)

__device__ __forceinline__ u16 f2bf(float f) {
  unsigned int u = __builtin_bit_cast(unsigned int, f);
  u += 0x7FFFu + ((u >> 16) & 1u);
  return (u16)(u >> 16);
}
__device__ __forceinline__ float bf2f(u16 h) {
  return __builtin_bit_cast(float, (u32)h << 16);
}

// ---------------------------------------------------------------- f32 -> bf16
__global__ __launch_bounds__(256) void f2b_kernel(const float* __restrict__ in,
                                                  u16* __restrict__ out, int n4) {
  int i = blockIdx.x * 256 + threadIdx.x;
  if (i < n4) {
    f32x4 v = *(const f32x4*)(in + (size_t)i * 4);
    u16x4 o;
    o[0] = f2bf(v[0]); o[1] = f2bf(v[1]); o[2] = f2bf(v[2]); o[3] = f2bf(v[3]);
    *(u16x4*)(out + (size_t)i * 4) = o;
  }
}

// all 4 weight matrices in one launch; dst regions contiguous (1M elems each)
__global__ __launch_bounds__(256) void f2bw_kernel(const float* __restrict__ s0,
    const float* __restrict__ s1, const float* __restrict__ s2,
    const float* __restrict__ s3, u16* __restrict__ dst) {
  const int y = blockIdx.y;
  const float* s = (y == 0) ? s0 : ((y == 1) ? s1 : ((y == 2) ? s2 : s3));
  int i = blockIdx.x * 256 + threadIdx.x;
  f32x4 v = *(const f32x4*)(s + (size_t)i * 4);
  u16x4 o;
  o[0] = f2bf(v[0]); o[1] = f2bf(v[1]); o[2] = f2bf(v[2]); o[3] = f2bf(v[3]);
  *(u16x4*)(dst + (size_t)y * 1048576 + (size_t)i * 4) = o;
}

// --------------------------------------------- NT GEMM core: C = A * W^T
// 128x128 tile, BK=32, 256 thr (4 waves). 3-buffer counted-vmcnt pipeline.
__device__ __forceinline__ void gemm_core(const u16* __restrict__ A,
                                          const u16* __restrict__ W,
                                          int bm0, int bn0,
                                          u16* ldsA, u16* ldsB,
                                          f32x4 acc[4][4]) {
  const int tid = threadIdx.x;
  const int l = tid & 63;
  const int lr = l & 15, lk = l >> 4;
  const int w = tid >> 6;
  const int wr = w >> 1, wc = w & 1;
  const int srow = tid >> 2, sko = (tid & 3) << 3;
  auto stage = [&](int kt, int buf) {  // 4 VMEM loads per thread
#pragma unroll
    for (int it = 0; it < 2; ++it) {
      int row = it * 64 + srow;
      GLOAD16(A + (size_t)(bm0 + row) * 1024 + kt * 32 + sko,
              ldsA + buf * 4096 + (it * 256 + tid) * 8);
      GLOAD16(W + (size_t)(bn0 + row) * 1024 + kt * 32 + sko,
              ldsB + buf * 4096 + (it * 256 + tid) * 8);
    }
  };
  stage(0, 0);
  stage(1, 1);
  int cur = 0, nx2 = 2;
  for (int kt = 0; kt < 32; ++kt) {
    if (kt < 31) asm volatile("s_waitcnt vmcnt(4)" ::: "memory");
    else         asm volatile("s_waitcnt vmcnt(0)" ::: "memory");
    __builtin_amdgcn_s_barrier();
    __builtin_amdgcn_sched_barrier(0);
    if (kt + 2 < 32) stage(kt + 2, nx2);
    const u16* lA = ldsA + cur * 4096;
    const u16* lB = ldsB + cur * 4096;
    bf16x8 af[4], bfr[4];
#pragma unroll
    for (int m = 0; m < 4; ++m)
      af[m] = *(const bf16x8*)(lA + (wr * 64 + m * 16 + lr) * 32 + lk * 8);
#pragma unroll
    for (int n = 0; n < 4; ++n)
      bfr[n] = *(const bf16x8*)(lB + (wc * 64 + n * 16 + lr) * 32 + lk * 8);
#pragma unroll
    for (int m = 0; m < 4; ++m)
#pragma unroll
      for (int n = 0; n < 4; ++n)
        acc[m][n] = __builtin_amdgcn_mfma_f32_16x16x32_bf16(af[m], bfr[n], acc[m][n], 0, 0, 0);
    cur = (cur == 2) ? 0 : cur + 1;
    nx2 = (nx2 == 2) ? 0 : nx2 + 1;
  }
}

// --------------------------------------------- fused QKV projection
// z=0: Q -> Qb rows; z=1: K -> Kb rows; z=2: V -> V-frag [bh][t][ks][half][lane][8]
__global__ __launch_bounds__(256) void qkv_gemm(const u16* __restrict__ xb,
    const u16* __restrict__ wq, const u16* __restrict__ wk, const u16* __restrict__ wv,
    const float* __restrict__ bq, const float* __restrict__ bk, const float* __restrict__ bv,
    u16* __restrict__ Qb, u16* __restrict__ Kb, u16* __restrict__ Vf) {
  __shared__ u16 ldsA[3 * 4096];
  __shared__ u16 ldsB[3 * 4096];
  const int z = blockIdx.z;
  const u16* W = (z == 0) ? wq : ((z == 1) ? wk : wv);
  const float* bias = (z == 0) ? bq : ((z == 1) ? bk : bv);
  const int bm0 = blockIdx.x * 128, bn0 = blockIdx.y * 128;
  const f32x4 zf = {0.f, 0.f, 0.f, 0.f};
  f32x4 acc[4][4];
#pragma unroll
  for (int m = 0; m < 4; ++m)
#pragma unroll
    for (int n = 0; n < 4; ++n) acc[m][n] = zf;
  gemm_core(xb, W, bm0, bn0, ldsA, ldsB, acc);
  const int tid = threadIdx.x, l = tid & 63, lr = l & 15, lk = l >> 4;
  const int w = tid >> 6, wr = w >> 1, wc = w & 1;
  float bcol[4];
#pragma unroll
  for (int n = 0; n < 4; ++n) bcol[n] = bias[bn0 + wc * 64 + n * 16 + lr];
  if (z < 2) {
    u16* outp = z ? Kb : Qb;
#pragma unroll
    for (int m = 0; m < 4; ++m)
#pragma unroll
      for (int n = 0; n < 4; ++n)
#pragma unroll
        for (int r = 0; r < 4; ++r) {
          int row = bm0 + wr * 64 + m * 16 + lk * 4 + r;
          int col = bn0 + wc * 64 + n * 16 + lr;
          outp[(size_t)row * 1024 + col] = f2bf(acc[m][n][r] + bcol[n]);
        }
  } else {
    // V-frag: element (hd, key): t=key>>6, kin=key&63, ks=kin>>4, hi=(kin>>3)&1,
    // j=kin&7, vhalf=hd>>5, lq=hd&31.
#pragma unroll
    for (int m = 0; m < 4; ++m)
#pragma unroll
      for (int n = 0; n < 4; ++n) {
        int row = bm0 + wr * 64 + m * 16 + lk * 4;   // key base (r = 0..3)
        int col = bn0 + wc * 64 + n * 16 + lr;
        int b = row >> 11, sf = row & 2047, hh = col >> 6, hd = col & 63;
        int t = sf >> 6, kin = sf & 63;
        int ks = kin >> 4, hiv = (kin >> 3) & 1, j0 = kin & 7;
        int vhalf = hd >> 5, lq = hd & 31;
        u16x4 o;
#pragma unroll
        for (int r = 0; r < 4; ++r) o[r] = f2bf(acc[m][n][r] + bcol[n]);
        size_t addr = (size_t)(b * 16 + hh) * 131072 +
                      (size_t)(((t * 4 + ks) * 2 + vhalf)) * 512 +
                      ((hiv << 5) + lq) * 8 + j0;
        *(u16x4*)(Vf + addr) = o;
      }
  }
}

// --------------------------------------------- output projection
__global__ __launch_bounds__(256) void proj_gemm(const u16* __restrict__ ctx,
    const u16* __restrict__ wo, const float* __restrict__ bo, float* __restrict__ out) {
  __shared__ u16 ldsA[3 * 4096];
  __shared__ u16 ldsB[3 * 4096];
  const int bm0 = blockIdx.x * 128, bn0 = blockIdx.y * 128;
  const f32x4 zf = {0.f, 0.f, 0.f, 0.f};
  f32x4 acc[4][4];
#pragma unroll
  for (int m = 0; m < 4; ++m)
#pragma unroll
    for (int n = 0; n < 4; ++n) acc[m][n] = zf;
  gemm_core(ctx, wo, bm0, bn0, ldsA, ldsB, acc);
  const int tid = threadIdx.x, l = tid & 63, lr = l & 15, lk = l >> 4;
  const int w = tid >> 6, wr = w >> 1, wc = w & 1;
  float bcol[4];
#pragma unroll
  for (int n = 0; n < 4; ++n) bcol[n] = bo[bn0 + wc * 64 + n * 16 + lr];
#pragma unroll
  for (int m = 0; m < 4; ++m)
#pragma unroll
    for (int n = 0; n < 4; ++n)
#pragma unroll
      for (int r = 0; r < 4; ++r) {
        int row = bm0 + wr * 64 + m * 16 + lk * 4 + r;
        int col = bn0 + wc * 64 + n * 16 + lr;
        out[(size_t)row * 1024 + col] = acc[m][n][r] + bcol[n];
      }
}

// --------------------------------------------- RMSNorm + RoPE -> fragment layouts
// which==0 (q): fold 0.125*log2(e); Q-frag [bh][q>>5][hs][lane][8]
// which==1 (k): K-frag [bh][t][hs][khalf][lane][8]
__global__ __launch_bounds__(256) void rmsrope(const u16* __restrict__ Qb,
    const u16* __restrict__ Kb, const float* __restrict__ gq, const float* __restrict__ gk,
    const float* __restrict__ fc, const float* __restrict__ fs,
    u16* __restrict__ Qf, u16* __restrict__ Kf) {
  const int row = blockIdx.x;
  const int which = blockIdx.y;
  const u16* src = (which ? Kb : Qb) + (size_t)row * 1024;
  const float* g = which ? gk : gq;
  const int t = threadIdx.x;
  u16x4 raw = *(const u16x4*)(src + t * 4);
  float v0 = bf2f(raw[0]), v1 = bf2f(raw[1]), v2 = bf2f(raw[2]), v3 = bf2f(raw[3]);
  float ss = v0 * v0 + v1 * v1 + v2 * v2 + v3 * v3;
#pragma unroll
  for (int mm = 1; mm < 64; mm <<= 1) ss += __shfl_xor(ss, mm);
  __shared__ float red[4];
  if ((t & 63) == 0) red[t >> 6] = ss;
  __syncthreads();
  float rstd = rsqrtf((red[0] + red[1] + red[2] + red[3]) * (1.0f / 1024.0f) + 1e-6f);
  if (!which) rstd *= 0.18033688011112042f;   // 0.125 * log2(e) folded into q
  int d = t * 4, hh = d >> 6, dh = d & 63, p = dh >> 1;
  int s = row & 2047, b = row >> 11;
  float c0 = fc[(s << 5) + p], s0 = fs[(s << 5) + p];
  float c1 = fc[(s << 5) + p + 1], s1 = fs[(s << 5) + p + 1];
  float x0 = v0 * rstd * g[d];
  float x1 = v1 * rstd * g[d + 1];
  float x2 = v2 * rstd * g[d + 2];
  float x3 = v3 * rstd * g[d + 3];
  u16x4 o;
  o[0] = f2bf(x0 * c0 - x1 * s0);
  o[1] = f2bf(x0 * s0 + x1 * c0);
  o[2] = f2bf(x2 * c1 - x3 * s1);
  o[3] = f2bf(x2 * s1 + x3 * c1);
  const size_t base = (size_t)(b * 16 + hh) * 131072;
  const int hs = dh >> 4, hi = (dh >> 3) & 1, j0 = dh & 7;
  size_t addr;
  if (!which) {
    addr = base + (size_t)((s >> 5) * 4 + hs) * 512 + ((hi << 5) + (s & 31)) * 8 + j0;
  } else {
    addr = base + (size_t)(((s >> 6) * 4 + hs) * 2 + ((s >> 5) & 1)) * 512 +
           ((hi << 5) + (s & 31)) * 8 + j0;
  }
  *(u16x4*)((which ? Kf : Qf) + addr) = o;
}

// --------------------------------------------- flash attention (non-causal)
// 512 blocks x 256 thr = 4 independent waves (no LDS, no barriers), R10 math.
// In-wave ILP pipeline: QK(t+1) runs BEFORE softmax+PV(t) each sub-iter, so
// the two MFMA chains + exp2 VALU block are independent and interleave
// (R14 diagnosis: dependent-MFMA chain latency, not occupancy, is the bound).
// exp2 via __builtin_amdgcn_exp2f = bare v_exp_f32 (no libm expansion).
__global__ __launch_bounds__(256) void attn_kernel(const u16* __restrict__ Qf,
    const u16* __restrict__ Kf, const u16* __restrict__ Vf, u16* __restrict__ ctx) {
  const int tid = threadIdx.x;
  const int w = tid >> 6, l = tid & 63;
  const int lq = l & 31, hi = l >> 5;
  const bool hiB = (hi != 0);
  const int id = blockIdx.x;
  const int qt = (id >> 3) & 15;
  const int hb = (id & 7) | ((id >> 7) << 3);
  const int h = hb & 15, b = hb >> 4;
  const int bh = b * 16 + h;
  const u16* Qp = Qf + (size_t)bh * 131072;
  const u16* Kp = Kf + (size_t)bh * 131072;
  const u16* Vp = Vf + (size_t)bh * 131072;
  bf16x8 qf[4];
#pragma unroll
  for (int hs = 0; hs < 4; ++hs)
    qf[hs] = *(const bf16x8*)(Qp + (size_t)((qt * 4 + w) * 4 + hs) * 512 + l * 8);

  auto ldK = [&](int t, bf16x8* kr) {
#pragma unroll
    for (int i = 0; i < 8; ++i)
      kr[i] = *(const bf16x8*)(Kp + ((size_t)t * 8 + i) * 512 + l * 8);
  };
  auto ldV = [&](int t, bf16x8* vr) {
#pragma unroll
    for (int i = 0; i < 8; ++i)
      vr[i] = *(const bf16x8*)(Vp + ((size_t)t * 8 + i) * 512 + l * 8);
  };

  const f32x16 z16 = {0,0,0,0, 0,0,0,0, 0,0,0,0, 0,0,0,0};
  f32x16 O0 = z16, O1 = z16;
  float lsum = 0.f;

  auto qk_step = [&](const bf16x8* kr, f32x16& s0, f32x16& s1) {
    s0 = z16; s1 = z16;
    __builtin_amdgcn_s_setprio(1);
#pragma unroll
    for (int hs = 0; hs < 4; ++hs) {
      s0 = __builtin_amdgcn_mfma_f32_32x32x16_bf16(kr[hs * 2 + 0], qf[hs], s0, 0, 0, 0);
      s1 = __builtin_amdgcn_mfma_f32_32x32x16_bf16(kr[hs * 2 + 1], qf[hs], s1, 0, 0, 0);
    }
    __builtin_amdgcn_s_setprio(0);
  };

  auto sm_pv = [&](const bf16x8* vr, f32x16& sc0, f32x16& sc1) {
    float rs = 0.f;
    u32 pk0[8], pk1[8];                          // pk(exp2 sc[2m], exp2 sc[2m+1])
#pragma unroll
    for (int m = 0; m < 8; ++m) {
      float a0 = __builtin_amdgcn_exp2f(sc0[2 * m]);
      float a1 = __builtin_amdgcn_exp2f(sc0[2 * m + 1]);
      float c0 = __builtin_amdgcn_exp2f(sc1[2 * m]);
      float c1 = __builtin_amdgcn_exp2f(sc1[2 * m + 1]);
      rs += (a0 + a1) + (c0 + c1);
      bf16x2 pA; pA[0] = (__bf16)a0; pA[1] = (__bf16)a1;
      bf16x2 pC; pC[0] = (__bf16)c0; pC[1] = (__bf16)c1;
      pk0[m] = __builtin_bit_cast(u32, pA);
      pk1[m] = __builtin_bit_cast(u32, pC);
    }
    rs += __shfl_xor(rs, 32);
    lsum += rs;
    // direction-proof half exchange (R7): pb[ks] elem j = P[16ks+8hi+j][lq]
    auto xchg = [&](u32 X, u32 Y, u32& wlo, u32& whi) {
      u32 s1v = hiB ? X : Y;
      u32 r = (u32)__shfl_xor((int)s1v, 32);
      wlo = hiB ? r : X;
      whi = hiB ? Y : r;
    };
    bf16x8 pb[4];
    {
      u32 w0, w1, w2, w3;
      xchg(pk0[0], pk0[2], w0, w2);
      xchg(pk0[1], pk0[3], w1, w3);
      u32x4 pw = {w0, w1, w2, w3};
      pb[0] = __builtin_bit_cast(bf16x8, pw);
      xchg(pk0[4], pk0[6], w0, w2);
      xchg(pk0[5], pk0[7], w1, w3);
      u32x4 pw1 = {w0, w1, w2, w3};
      pb[1] = __builtin_bit_cast(bf16x8, pw1);
      xchg(pk1[0], pk1[2], w0, w2);
      xchg(pk1[1], pk1[3], w1, w3);
      u32x4 pw2 = {w0, w1, w2, w3};
      pb[2] = __builtin_bit_cast(bf16x8, pw2);
      xchg(pk1[4], pk1[6], w0, w2);
      xchg(pk1[5], pk1[7], w1, w3);
      u32x4 pw3 = {w0, w1, w2, w3};
      pb[3] = __builtin_bit_cast(bf16x8, pw3);
    }
    __builtin_amdgcn_s_setprio(1);
#pragma unroll
    for (int ks = 0; ks < 4; ++ks) {
      O0 = __builtin_amdgcn_mfma_f32_32x32x16_bf16(vr[ks * 2 + 0], pb[ks], O0, 0, 0, 0);
      O1 = __builtin_amdgcn_mfma_f32_32x32x16_bf16(vr[ks * 2 + 1], pb[ks], O1, 0, 0, 0);
    }
    __builtin_amdgcn_s_setprio(0);
  };

  // named double buffers; K loads 2-ahead (qk(t+1) runs in sub-iter t), V 1-ahead
  bf16x8 kE[8], kO[8], vE[8], vO[8];
  f32x16 scA0, scA1, scB0, scB1;
  ldK(0, kE);
  ldV(0, vE);
  ldK(1, kO);
  qk_step(kE, scA0, scA1);                 // scores for tile 0
#pragma unroll 1
  for (int dt = 0; dt < 16; ++dt) {
    const int t = dt * 2;
    {   // sub-iter t (even): qk(t+1) from kO -> scB; then softmax+PV(t) from scA,vE
      if (t + 2 < 32) ldK(t + 2, kE);      // kE dead after qk(t) last sub-iter
      ldV(t + 1, vO);                      // t+1 <= 31 always (t <= 30)
      qk_step(kO, scB0, scB1);
      sm_pv(vE, scA0, scA1);
    }
    {   // sub-iter t+1 (odd): qk(t+2) from kE -> scA; then softmax+PV(t+1)
      if (t + 3 < 32) ldK(t + 3, kO);
      if (t + 2 < 32) {
        ldV(t + 2, vE);
        qk_step(kE, scA0, scA1);
      }
      sm_pv(vO, scB0, scB1);
    }
  }
  float inv = 1.0f / lsum;
  const int q0 = qt * 128 + w * 32;
  const size_t rowoff = ((size_t)(b * 2048 + q0 + lq)) * 1024 + h * 64;
#pragma unroll
  for (int g = 0; g < 4; ++g) {                 // hd = 8g + 4hi + rr (+32 for O1)
    u16x4 oa, ob;
#pragma unroll
    for (int rr = 0; rr < 4; ++rr) {
      oa[rr] = f2bf(O0[4 * g + rr] * inv);
      ob[rr] = f2bf(O1[4 * g + rr] * inv);
    }
    *(u16x4*)(ctx + rowoff + 8 * g + 4 * hi) = oa;
    *(u16x4*)(ctx + rowoff + 32 + 8 * g + 4 * hi) = ob;
  }
}

// ---------------------------------------------------------------- launch
extern "C" void kernel_launch(void* const* d_in, const int* in_sizes, int n_in,
                              void* d_out, int out_size, void* d_ws, size_t ws_size,
                              hipStream_t stream) {
  (void)in_sizes; (void)n_in; (void)out_size; (void)ws_size;
  const float* x  = (const float*)d_in[0];
  const float* Wq = (const float*)d_in[1];
  const float* bq = (const float*)d_in[2];
  const float* Wk = (const float*)d_in[3];
  const float* bk = (const float*)d_in[4];
  const float* Wv = (const float*)d_in[5];
  const float* bv = (const float*)d_in[6];
  const float* Wo = (const float*)d_in[7];
  const float* bo = (const float*)d_in[8];
  const float* gq = (const float*)d_in[9];
  const float* gk = (const float*)d_in[10];
  const float* fc = (const float*)d_in[11];
  const float* fs = (const float*)d_in[12];
  float* out = (float*)d_out;
  char* ws = (char*)d_ws;
  u16*  xb  = (u16*)(ws + 0);           //  8 MB  x bf16 [4096][1024]
  u16*  wqb = (u16*)(ws + 8388608);     //  2 MB each, contiguous x4
  u16*  wkb = (u16*)(ws + 10485760);
  u16*  wvb = (u16*)(ws + 12582912);
  u16*  wob = (u16*)(ws + 14680064);
  u16*  Qfb = (u16*)(ws + 16777216);    //  8 MB bf16 pre-norm q rows
  u16*  Kfb = (u16*)(ws + 25165824);    //  8 MB pre-norm k rows
  u16*  Qfr = (u16*)(ws + 33554432);    //  8 MB Q fragment-major
  u16*  Kfr = (u16*)(ws + 41943040);    //  8 MB K fragment-major
  u16*  Vfr = (u16*)(ws + 50331648);    //  8 MB V fragment-major
  u16*  ctx = (u16*)(ws + 58720256);    //  8 MB bf16 [B,S,D]

  f2b_kernel<<<4096, 256, 0, stream>>>(x, xb, 1048576);
  f2bw_kernel<<<dim3(1024, 4), 256, 0, stream>>>(Wq, Wk, Wv, Wo, wqb);
  qkv_gemm<<<dim3(32, 8, 3), 256, 0, stream>>>(xb, wqb, wkb, wvb, bq, bk, bv, Qfb, Kfb, Vfr);
  rmsrope<<<dim3(4096, 2), 256, 0, stream>>>(Qfb, Kfb, gq, gk, fc, fs, Qfr, Kfr);
  attn_kernel<<<512, 256, 0, stream>>>(Qfr, Kfr, Vfr, ctx);
  proj_gemm<<<dim3(32, 8), 256, 0, stream>>>(ctx, wob, bo, out);
}

// Round 16
// 141.178 us; speedup vs baseline: 2.3535x; 1.0164x over previous
//
#include <hip/hip_runtime.h>

typedef unsigned short u16;
typedef unsigned int u32;
typedef u16 u16x4 __attribute__((ext_vector_type(4)));
typedef u16 u16x8 __attribute__((ext_vector_type(8)));
typedef u32 u32x4 __attribute__((ext_vector_type(4)));
typedef float f32x4 __attribute__((ext_vector_type(4)));
typedef float f32x16 __attribute__((ext_vector_type(16)));
typedef __bf16 bf16x2 __attribute__((ext_vector_type(2)));
typedef __bf16 bf16x8 __attribute__((ext_vector_type(8)));

#define GLOAD16(gp, lp)                                             \
  __builtin_amdgcn_global_load_lds(                                 \
      (const __attribute__((address_space(1))) void*)(gp),          \
      (__attribute__((address_space(3))) void*)(lp), 16, 0, 0)

__device__ __forceinline__ u16 f2bf(float f) {
  unsigned int u = __builtin_bit_cast(unsigned int, f);
  u += 0x7FFFu + ((u >> 16) & 1u);
  return (u16)(u >> 16);
}
__device__ __forceinline__ float bf2f(u16 h) {
  return __builtin_bit_cast(float, (u32)h << 16);
}

// ------------------------------------------- all f32->bf16 converts, 1 launch
// groups of 4 floats: [0,1048576) = x -> xb; then 4 weights -> wb contiguous
__global__ __launch_bounds__(256) void f2ball_kernel(const float* __restrict__ x,
    const float* __restrict__ w0, const float* __restrict__ w1,
    const float* __restrict__ w2, const float* __restrict__ w3,
    u16* __restrict__ xb, u16* __restrict__ wb) {
  int g = blockIdx.x * 256 + threadIdx.x;
  const float* s;
  u16* d;
  size_t off;
  if (g < 1048576) {
    s = x; d = xb; off = (size_t)g * 4;
  } else {
    int wi = g - 1048576;
    int sel = wi >> 18;
    int r = wi & 262143;
    s = (sel == 0) ? w0 : ((sel == 1) ? w1 : ((sel == 2) ? w2 : w3));
    d = wb + (size_t)sel * 1048576;
    off = (size_t)r * 4;
  }
  f32x4 v = *(const f32x4*)(s + off);
  u16x4 o;
  o[0] = f2bf(v[0]); o[1] = f2bf(v[1]); o[2] = f2bf(v[2]); o[3] = f2bf(v[3]);
  *(u16x4*)(d + off) = o;
}

// --------------------------------------------- NT GEMM core: C = A * W^T
// 128x128 tile, BK=32, 256 thr (4 waves). 3-buffer counted-vmcnt pipeline.
__device__ __forceinline__ void gemm_core(const u16* __restrict__ A,
                                          const u16* __restrict__ W,
                                          int bm0, int bn0,
                                          u16* ldsA, u16* ldsB,
                                          f32x4 acc[4][4]) {
  const int tid = threadIdx.x;
  const int l = tid & 63;
  const int lr = l & 15, lk = l >> 4;
  const int w = tid >> 6;
  const int wr = w >> 1, wc = w & 1;
  const int srow = tid >> 2, sko = (tid & 3) << 3;
  auto stage = [&](int kt, int buf) {  // 4 VMEM loads per thread
#pragma unroll
    for (int it = 0; it < 2; ++it) {
      int row = it * 64 + srow;
      GLOAD16(A + (size_t)(bm0 + row) * 1024 + kt * 32 + sko,
              ldsA + buf * 4096 + (it * 256 + tid) * 8);
      GLOAD16(W + (size_t)(bn0 + row) * 1024 + kt * 32 + sko,
              ldsB + buf * 4096 + (it * 256 + tid) * 8);
    }
  };
  stage(0, 0);
  stage(1, 1);
  int cur = 0, nx2 = 2;
  for (int kt = 0; kt < 32; ++kt) {
    if (kt < 31) asm volatile("s_waitcnt vmcnt(4)" ::: "memory");
    else         asm volatile("s_waitcnt vmcnt(0)" ::: "memory");
    __builtin_amdgcn_s_barrier();
    __builtin_amdgcn_sched_barrier(0);
    if (kt + 2 < 32) stage(kt + 2, nx2);
    const u16* lA = ldsA + cur * 4096;
    const u16* lB = ldsB + cur * 4096;
    bf16x8 af[4], bfr[4];
#pragma unroll
    for (int m = 0; m < 4; ++m)
      af[m] = *(const bf16x8*)(lA + (wr * 64 + m * 16 + lr) * 32 + lk * 8);
#pragma unroll
    for (int n = 0; n < 4; ++n)
      bfr[n] = *(const bf16x8*)(lB + (wc * 64 + n * 16 + lr) * 32 + lk * 8);
#pragma unroll
    for (int m = 0; m < 4; ++m)
#pragma unroll
      for (int n = 0; n < 4; ++n)
        acc[m][n] = __builtin_amdgcn_mfma_f32_16x16x32_bf16(af[m], bfr[n], acc[m][n], 0, 0, 0);
    cur = (cur == 2) ? 0 : cur + 1;
    nx2 = (nx2 == 2) ? 0 : nx2 + 1;
  }
}

// --------------------------------------------- fused QKV projection
// z=0: Q -> Qb rows; z=1: K -> Kb rows; z=2: V -> V-frag [bh][t][ks][half][lane][8]
__global__ __launch_bounds__(256) void qkv_gemm(const u16* __restrict__ xb,
    const u16* __restrict__ wq, const u16* __restrict__ wk, const u16* __restrict__ wv,
    const float* __restrict__ bq, const float* __restrict__ bk, const float* __restrict__ bv,
    u16* __restrict__ Qb, u16* __restrict__ Kb, u16* __restrict__ Vf) {
  __shared__ u16 ldsA[3 * 4096];
  __shared__ u16 ldsB[3 * 4096];
  const int z = blockIdx.z;
  const u16* W = (z == 0) ? wq : ((z == 1) ? wk : wv);
  const float* bias = (z == 0) ? bq : ((z == 1) ? bk : bv);
  const int bm0 = blockIdx.x * 128, bn0 = blockIdx.y * 128;
  const f32x4 zf = {0.f, 0.f, 0.f, 0.f};
  f32x4 acc[4][4];
#pragma unroll
  for (int m = 0; m < 4; ++m)
#pragma unroll
    for (int n = 0; n < 4; ++n) acc[m][n] = zf;
  gemm_core(xb, W, bm0, bn0, ldsA, ldsB, acc);
  const int tid = threadIdx.x, l = tid & 63, lr = l & 15, lk = l >> 4;
  const int w = tid >> 6, wr = w >> 1, wc = w & 1;
  float bcol[4];
#pragma unroll
  for (int n = 0; n < 4; ++n) bcol[n] = bias[bn0 + wc * 64 + n * 16 + lr];
  if (z < 2) {
    u16* outp = z ? Kb : Qb;
#pragma unroll
    for (int m = 0; m < 4; ++m)
#pragma unroll
      for (int n = 0; n < 4; ++n)
#pragma unroll
        for (int r = 0; r < 4; ++r) {
          int row = bm0 + wr * 64 + m * 16 + lk * 4 + r;
          int col = bn0 + wc * 64 + n * 16 + lr;
          outp[(size_t)row * 1024 + col] = f2bf(acc[m][n][r] + bcol[n]);
        }
  } else {
    // V-frag: element (hd, key): t=key>>6, kin=key&63, ks=kin>>4, hi=(kin>>3)&1,
    // j=kin&7, vhalf=hd>>5, lq=hd&31.
#pragma unroll
    for (int m = 0; m < 4; ++m)
#pragma unroll
      for (int n = 0; n < 4; ++n) {
        int row = bm0 + wr * 64 + m * 16 + lk * 4;   // key base (r = 0..3)
        int col = bn0 + wc * 64 + n * 16 + lr;
        int b = row >> 11, sf = row & 2047, hh = col >> 6, hd = col & 63;
        int t = sf >> 6, kin = sf & 63;
        int ks = kin >> 4, hiv = (kin >> 3) & 1, j0 = kin & 7;
        int vhalf = hd >> 5, lq = hd & 31;
        u16x4 o;
#pragma unroll
        for (int r = 0; r < 4; ++r) o[r] = f2bf(acc[m][n][r] + bcol[n]);
        size_t addr = (size_t)(b * 16 + hh) * 131072 +
                      (size_t)(((t * 4 + ks) * 2 + vhalf)) * 512 +
                      ((hiv << 5) + lq) * 8 + j0;
        *(u16x4*)(Vf + addr) = o;
      }
  }
}

// --------------------------------------------- output projection
__global__ __launch_bounds__(256) void proj_gemm(const u16* __restrict__ ctx,
    const u16* __restrict__ wo, const float* __restrict__ bo, float* __restrict__ out) {
  __shared__ u16 ldsA[3 * 4096];
  __shared__ u16 ldsB[3 * 4096];
  const int bm0 = blockIdx.x * 128, bn0 = blockIdx.y * 128;
  const f32x4 zf = {0.f, 0.f, 0.f, 0.f};
  f32x4 acc[4][4];
#pragma unroll
  for (int m = 0; m < 4; ++m)
#pragma unroll
    for (int n = 0; n < 4; ++n) acc[m][n] = zf;
  gemm_core(ctx, wo, bm0, bn0, ldsA, ldsB, acc);
  const int tid = threadIdx.x, l = tid & 63, lr = l & 15, lk = l >> 4;
  const int w = tid >> 6, wr = w >> 1, wc = w & 1;
  float bcol[4];
#pragma unroll
  for (int n = 0; n < 4; ++n) bcol[n] = bo[bn0 + wc * 64 + n * 16 + lr];
#pragma unroll
  for (int m = 0; m < 4; ++m)
#pragma unroll
    for (int n = 0; n < 4; ++n)
#pragma unroll
      for (int r = 0; r < 4; ++r) {
        int row = bm0 + wr * 64 + m * 16 + lk * 4 + r;
        int col = bn0 + wc * 64 + n * 16 + lr;
        out[(size_t)row * 1024 + col] = acc[m][n][r] + bcol[n];
      }
}

// --------------------------------------------- RMSNorm + RoPE -> fragment layouts
// which==0 (q): fold 0.125*log2(e); Q-frag [bh][q>>5][hs][lane][8]
// which==1 (k): K-frag [bh][t][hs][khalf][lane][8]
__global__ __launch_bounds__(256) void rmsrope(const u16* __restrict__ Qb,
    const u16* __restrict__ Kb, const float* __restrict__ gq, const float* __restrict__ gk,
    const float* __restrict__ fc, const float* __restrict__ fs,
    u16* __restrict__ Qf, u16* __restrict__ Kf) {
  const int row = blockIdx.x;
  const int which = blockIdx.y;
  const u16* src = (which ? Kb : Qb) + (size_t)row * 1024;
  const float* g = which ? gk : gq;
  const int t = threadIdx.x;
  u16x4 raw = *(const u16x4*)(src + t * 4);
  float v0 = bf2f(raw[0]), v1 = bf2f(raw[1]), v2 = bf2f(raw[2]), v3 = bf2f(raw[3]);
  float ss = v0 * v0 + v1 * v1 + v2 * v2 + v3 * v3;
#pragma unroll
  for (int mm = 1; mm < 64; mm <<= 1) ss += __shfl_xor(ss, mm);
  __shared__ float red[4];
  if ((t & 63) == 0) red[t >> 6] = ss;
  __syncthreads();
  float rstd = rsqrtf((red[0] + red[1] + red[2] + red[3]) * (1.0f / 1024.0f) + 1e-6f);
  if (!which) rstd *= 0.18033688011112042f;   // 0.125 * log2(e) folded into q
  int d = t * 4, hh = d >> 6, dh = d & 63, p = dh >> 1;
  int s = row & 2047, b = row >> 11;
  float c0 = fc[(s << 5) + p], s0 = fs[(s << 5) + p];
  float c1 = fc[(s << 5) + p + 1], s1 = fs[(s << 5) + p + 1];
  float x0 = v0 * rstd * g[d];
  float x1 = v1 * rstd * g[d + 1];
  float x2 = v2 * rstd * g[d + 2];
  float x3 = v3 * rstd * g[d + 3];
  u16x4 o;
  o[0] = f2bf(x0 * c0 - x1 * s0);
  o[1] = f2bf(x0 * s0 + x1 * c0);
  o[2] = f2bf(x2 * c1 - x3 * s1);
  o[3] = f2bf(x2 * s1 + x3 * c1);
  const size_t base = (size_t)(b * 16 + hh) * 131072;
  const int hs = dh >> 4, hi = (dh >> 3) & 1, j0 = dh & 7;
  size_t addr;
  if (!which) {
    addr = base + (size_t)((s >> 5) * 4 + hs) * 512 + ((hi << 5) + (s & 31)) * 8 + j0;
  } else {
    addr = base + (size_t)(((s >> 6) * 4 + hs) * 2 + ((s >> 5) & 1)) * 512 +
           ((hi << 5) + (s & 31)) * 8 + j0;
  }
  *(u16x4*)((which ? Kf : Qf) + addr) = o;
}

// --------------------------------------------- flash attention (non-causal)
// 512 blocks x 256 thr (4 waves, 128 q-rows). R16: K tile staged in LDS ONCE
// per block (gload_lds, 3-buffer counted vmcnt, single barrier/iter -- the
// proven gemm_core schedule). V stays per-wave direct-global (latency hides
// under QK+exp2; issued before stageK so the V-wait keeps K-stage in flight).
// Cuts per-CU VMEM 128->40 KB/iter (R15 diagnosis: redundant-VMEM bound).
__global__ __launch_bounds__(256) void attn_kernel(const u16* __restrict__ Qf,
    const u16* __restrict__ Kf, const u16* __restrict__ Vf, u16* __restrict__ ctx) {
  __shared__ u16 Kbuf[3][4096];    // 3 x 8KB K tiles, linear copy of K-frag
  const int tid = threadIdx.x;
  const int w = tid >> 6, l = tid & 63;
  const int lq = l & 31, hi = l >> 5;
  const bool hiB = (hi != 0);
  const int id = blockIdx.x;
  const int qt = (id >> 3) & 15;
  const int hb = (id & 7) | ((id >> 7) << 3);
  const int h = hb & 15, b = hb >> 4;
  const int bh = b * 16 + h;
  const u16* Qp = Qf + (size_t)bh * 131072;
  const u16* Kp = Kf + (size_t)bh * 131072;
  const u16* Vp = Vf + (size_t)bh * 131072;
  bf16x8 qf[4];
#pragma unroll
  for (int hs = 0; hs < 4; ++hs)
    qf[hs] = *(const bf16x8*)(Qp + (size_t)((qt * 4 + w) * 4 + hs) * 512 + l * 8);

  auto stageK = [&](int t, int buf) {    // 2 gload_lds per thread (8KB/block)
    GLOAD16(Kp + (size_t)t * 4096 + tid * 8, &Kbuf[buf][tid * 8]);
    GLOAD16(Kp + (size_t)t * 4096 + 2048 + tid * 8, &Kbuf[buf][2048 + tid * 8]);
  };
  auto ldV = [&](int t, bf16x8* vr) {    // 8 direct global loads per wave
#pragma unroll
    for (int i = 0; i < 8; ++i)
      vr[i] = *(const bf16x8*)(Vp + ((size_t)t * 8 + i) * 512 + l * 8);
  };

  const f32x16 z16 = {0,0,0,0, 0,0,0,0, 0,0,0,0, 0,0,0,0};
  f32x16 O0 = z16, O1 = z16;
  float lsum = 0.f;

  auto qk_lds = [&](const u16* Kb_, f32x16& s0, f32x16& s1) {
    s0 = z16; s1 = z16;
    __builtin_amdgcn_s_setprio(1);
#pragma unroll
    for (int hs = 0; hs < 4; ++hs) {
      bf16x8 k0 = *(const bf16x8*)(Kb_ + (hs * 2 + 0) * 512 + l * 8);
      bf16x8 k1 = *(const bf16x8*)(Kb_ + (hs * 2 + 1) * 512 + l * 8);
      s0 = __builtin_amdgcn_mfma_f32_32x32x16_bf16(k0, qf[hs], s0, 0, 0, 0);
      s1 = __builtin_amdgcn_mfma_f32_32x32x16_bf16(k1, qf[hs], s1, 0, 0, 0);
    }
    __builtin_amdgcn_s_setprio(0);
  };

  auto sm_pv = [&](const bf16x8* vr, f32x16& sc0, f32x16& sc1) {
    float rs = 0.f;
    u32 pk0[8], pk1[8];
#pragma unroll
    for (int m = 0; m < 8; ++m) {
      float a0 = __builtin_amdgcn_exp2f(sc0[2 * m]);
      float a1 = __builtin_amdgcn_exp2f(sc0[2 * m + 1]);
      float c0 = __builtin_amdgcn_exp2f(sc1[2 * m]);
      float c1 = __builtin_amdgcn_exp2f(sc1[2 * m + 1]);
      rs += (a0 + a1) + (c0 + c1);
      bf16x2 pA; pA[0] = (__bf16)a0; pA[1] = (__bf16)a1;
      bf16x2 pC; pC[0] = (__bf16)c0; pC[1] = (__bf16)c1;
      pk0[m] = __builtin_bit_cast(u32, pA);
      pk1[m] = __builtin_bit_cast(u32, pC);
    }
    rs += __shfl_xor(rs, 32);
    lsum += rs;
    // direction-proof half exchange (R7): pb[ks] elem j = P[16ks+8hi+j][lq]
    auto xchg = [&](u32 X, u32 Y, u32& wlo, u32& whi) {
      u32 s1v = hiB ? X : Y;
      u32 r = (u32)__shfl_xor((int)s1v, 32);
      wlo = hiB ? r : X;
      whi = hiB ? Y : r;
    };
    bf16x8 pb[4];
    {
      u32 w0, w1, w2, w3;
      xchg(pk0[0], pk0[2], w0, w2);
      xchg(pk0[1], pk0[3], w1, w3);
      u32x4 pw = {w0, w1, w2, w3};
      pb[0] = __builtin_bit_cast(bf16x8, pw);
      xchg(pk0[4], pk0[6], w0, w2);
      xchg(pk0[5], pk0[7], w1, w3);
      u32x4 pw1 = {w0, w1, w2, w3};
      pb[1] = __builtin_bit_cast(bf16x8, pw1);
      xchg(pk1[0], pk1[2], w0, w2);
      xchg(pk1[1], pk1[3], w1, w3);
      u32x4 pw2 = {w0, w1, w2, w3};
      pb[2] = __builtin_bit_cast(bf16x8, pw2);
      xchg(pk1[4], pk1[6], w0, w2);
      xchg(pk1[5], pk1[7], w1, w3);
      u32x4 pw3 = {w0, w1, w2, w3};
      pb[3] = __builtin_bit_cast(bf16x8, pw3);
    }
    __builtin_amdgcn_s_setprio(1);
#pragma unroll
    for (int ks = 0; ks < 4; ++ks) {
      O0 = __builtin_amdgcn_mfma_f32_32x32x16_bf16(vr[ks * 2 + 0], pb[ks], O0, 0, 0, 0);
      O1 = __builtin_amdgcn_mfma_f32_32x32x16_bf16(vr[ks * 2 + 1], pb[ks], O1, 0, 0, 0);
    }
    __builtin_amdgcn_s_setprio(0);
  };

  bf16x8 vV[8];
  f32x16 scX0, scX1;
  stageK(0, 0);
  stageK(1, 1);
  int cur = 0, nx2 = 2;
#pragma unroll 1
  for (int t = 0; t < 32; ++t) {
    if (t < 31) asm volatile("s_waitcnt vmcnt(2)" ::: "memory");
    else        asm volatile("s_waitcnt vmcnt(0)" ::: "memory");
    __builtin_amdgcn_s_barrier();
    __builtin_amdgcn_sched_barrier(0);
    ldV(t, vV);                          // issued BEFORE stageK: V-wait leaves
    if (t + 2 < 32) stageK(t + 2, nx2);  // the younger K-stage in flight
    qk_lds(&Kbuf[cur][0], scX0, scX1);
    sm_pv(vV, scX0, scX1);
    cur = (cur == 2) ? 0 : cur + 1;
    nx2 = (nx2 == 2) ? 0 : nx2 + 1;
  }
  float inv = 1.0f / lsum;
  const int q0 = qt * 128 + w * 32;
  const size_t rowoff = ((size_t)(b * 2048 + q0 + lq)) * 1024 + h * 64;
#pragma unroll
  for (int g = 0; g < 4; ++g) {                 // hd = 8g + 4hi + rr (+32 for O1)
    u16x4 oa, ob;
#pragma unroll
    for (int rr = 0; rr < 4; ++rr) {
      oa[rr] = f2bf(O0[4 * g + rr] * inv);
      ob[rr] = f2bf(O1[4 * g + rr] * inv);
    }
    *(u16x4*)(ctx + rowoff + 8 * g + 4 * hi) = oa;
    *(u16x4*)(ctx + rowoff + 32 + 8 * g + 4 * hi) = ob;
  }
}

// ---------------------------------------------------------------- launch
extern "C" void kernel_launch(void* const* d_in, const int* in_sizes, int n_in,
                              void* d_out, int out_size, void* d_ws, size_t ws_size,
                              hipStream_t stream) {
  (void)in_sizes; (void)n_in; (void)out_size; (void)ws_size;
  const float* x  = (const float*)d_in[0];
  const float* Wq = (const float*)d_in[1];
  const float* bq = (const float*)d_in[2];
  const float* Wk = (const float*)d_in[3];
  const float* bk = (const float*)d_in[4];
  const float* Wv = (const float*)d_in[5];
  const float* bv = (const float*)d_in[6];
  const float* Wo = (const float*)d_in[7];
  const float* bo = (const float*)d_in[8];
  const float* gq = (const float*)d_in[9];
  const float* gk = (const float*)d_in[10];
  const float* fc = (const float*)d_in[11];
  const float* fs = (const float*)d_in[12];
  float* out = (float*)d_out;
  char* ws = (char*)d_ws;
  u16*  xb  = (u16*)(ws + 0);           //  8 MB  x bf16 [4096][1024]
  u16*  wqb = (u16*)(ws + 8388608);     //  2 MB each, contiguous x4
  u16*  wkb = (u16*)(ws + 10485760);
  u16*  wvb = (u16*)(ws + 12582912);
  u16*  wob = (u16*)(ws + 14680064);
  u16*  Qfb = (u16*)(ws + 16777216);    //  8 MB bf16 pre-norm q rows
  u16*  Kfb = (u16*)(ws + 25165824);    //  8 MB pre-norm k rows
  u16*  Qfr = (u16*)(ws + 33554432);    //  8 MB Q fragment-major
  u16*  Kfr = (u16*)(ws + 41943040);    //  8 MB K fragment-major
  u16*  Vfr = (u16*)(ws + 50331648);    //  8 MB V fragment-major
  u16*  ctx = (u16*)(ws + 58720256);    //  8 MB bf16 [B,S,D]

  f2ball_kernel<<<8192, 256, 0, stream>>>(x, Wq, Wk, Wv, Wo, xb, wqb);
  qkv_gemm<<<dim3(32, 8, 3), 256, 0, stream>>>(xb, wqb, wkb, wvb, bq, bk, bv, Qfb, Kfb, Vfr);
  rmsrope<<<dim3(4096, 2), 256, 0, stream>>>(Qfb, Kfb, gq, gk, fc, fs, Qfr, Kfr);
  attn_kernel<<<512, 256, 0, stream>>>(Qfr, Kfr, Vfr, ctx);
  proj_gemm<<<dim3(32, 8), 256, 0, stream>>>(ctx, wob, bo, out);
}

// Round 17
// 134.831 us; speedup vs baseline: 2.4643x; 1.0471x over previous
//
#include <hip/hip_runtime.h>

typedef unsigned short u16;
typedef unsigned int u32;
typedef u16 u16x4 __attribute__((ext_vector_type(4)));
typedef u16 u16x8 __attribute__((ext_vector_type(8)));
typedef u32 u32x4 __attribute__((ext_vector_type(4)));
typedef float f32x4 __attribute__((ext_vector_type(4)));
typedef float f32x16 __attribute__((ext_vector_type(16)));
typedef __bf16 bf16x2 __attribute__((ext_vector_type(2)));
typedef __bf16 bf16x8 __attribute__((ext_vector_type(8)));

#define GLOAD16(gp, lp)                                             \
  __builtin_amdgcn_global_load_lds(                                 \
      (const __attribute__((address_space(1))) void*)(gp),          \
      (__attribute__((address_space(3))) void*)(lp), 16, 0, 0)

__device__ __forceinline__ u16 f2bf(float f) {
  unsigned int u = __builtin_bit_cast(unsigned int, f);
  u += 0x7FFFu + ((u >> 16) & 1u);
  return (u16)(u >> 16);
}
__device__ __forceinline__ float bf2f(u16 h) {
  return __builtin_bit_cast(float, (u32)h << 16);
}

// ------------------------------------------- all f32->bf16 converts, 1 launch
__global__ __launch_bounds__(256) void f2ball_kernel(const float* __restrict__ x,
    const float* __restrict__ w0, const float* __restrict__ w1,
    const float* __restrict__ w2, const float* __restrict__ w3,
    u16* __restrict__ xb, u16* __restrict__ wb) {
  int g = blockIdx.x * 256 + threadIdx.x;
  const float* s;
  u16* d;
  size_t off;
  if (g < 1048576) {
    s = x; d = xb; off = (size_t)g * 4;
  } else {
    int wi = g - 1048576;
    int sel = wi >> 18;
    int r = wi & 262143;
    s = (sel == 0) ? w0 : ((sel == 1) ? w1 : ((sel == 2) ? w2 : w3));
    d = wb + (size_t)sel * 1048576;
    off = (size_t)r * 4;
  }
  f32x4 v = *(const f32x4*)(s + off);
  u16x4 o;
  o[0] = f2bf(v[0]); o[1] = f2bf(v[1]); o[2] = f2bf(v[2]); o[3] = f2bf(v[3]);
  *(u16x4*)(d + off) = o;
}

// --------------------------------------------- NT GEMM core: C = A * W^T
// 128x128 tile, BK=32, 256 thr (4 waves). 3-buffer counted-vmcnt pipeline.
__device__ __forceinline__ void gemm_core(const u16* __restrict__ A,
                                          const u16* __restrict__ W,
                                          int bm0, int bn0,
                                          u16* ldsA, u16* ldsB,
                                          f32x4 acc[4][4]) {
  const int tid = threadIdx.x;
  const int l = tid & 63;
  const int lr = l & 15, lk = l >> 4;
  const int w = tid >> 6;
  const int wr = w >> 1, wc = w & 1;
  const int srow = tid >> 2, sko = (tid & 3) << 3;
  auto stage = [&](int kt, int buf) {  // 4 VMEM loads per thread
#pragma unroll
    for (int it = 0; it < 2; ++it) {
      int row = it * 64 + srow;
      GLOAD16(A + (size_t)(bm0 + row) * 1024 + kt * 32 + sko,
              ldsA + buf * 4096 + (it * 256 + tid) * 8);
      GLOAD16(W + (size_t)(bn0 + row) * 1024 + kt * 32 + sko,
              ldsB + buf * 4096 + (it * 256 + tid) * 8);
    }
  };
  stage(0, 0);
  stage(1, 1);
  int cur = 0, nx2 = 2;
  for (int kt = 0; kt < 32; ++kt) {
    if (kt < 31) asm volatile("s_waitcnt vmcnt(4)" ::: "memory");
    else         asm volatile("s_waitcnt vmcnt(0)" ::: "memory");
    __builtin_amdgcn_s_barrier();
    __builtin_amdgcn_sched_barrier(0);
    if (kt + 2 < 32) stage(kt + 2, nx2);
    const u16* lA = ldsA + cur * 4096;
    const u16* lB = ldsB + cur * 4096;
    bf16x8 af[4], bfr[4];
#pragma unroll
    for (int m = 0; m < 4; ++m)
      af[m] = *(const bf16x8*)(lA + (wr * 64 + m * 16 + lr) * 32 + lk * 8);
#pragma unroll
    for (int n = 0; n < 4; ++n)
      bfr[n] = *(const bf16x8*)(lB + (wc * 64 + n * 16 + lr) * 32 + lk * 8);
#pragma unroll
    for (int m = 0; m < 4; ++m)
#pragma unroll
      for (int n = 0; n < 4; ++n)
        acc[m][n] = __builtin_amdgcn_mfma_f32_16x16x32_bf16(af[m], bfr[n], acc[m][n], 0, 0, 0);
    cur = (cur == 2) ? 0 : cur + 1;
    nx2 = (nx2 == 2) ? 0 : nx2 + 1;
  }
}

// --------------------------------------------- fused QKV projection
// z=0: Q -> Qb rows; z=1: K -> Kb rows; z=2: V -> V-frag [bh][t][ks][half][lane][8]
__global__ __launch_bounds__(256) void qkv_gemm(const u16* __restrict__ xb,
    const u16* __restrict__ wq, const u16* __restrict__ wk, const u16* __restrict__ wv,
    const float* __restrict__ bq, const float* __restrict__ bk, const float* __restrict__ bv,
    u16* __restrict__ Qb, u16* __restrict__ Kb, u16* __restrict__ Vf) {
  __shared__ u16 ldsA[3 * 4096];
  __shared__ u16 ldsB[3 * 4096];
  const int z = blockIdx.z;
  const u16* W = (z == 0) ? wq : ((z == 1) ? wk : wv);
  const float* bias = (z == 0) ? bq : ((z == 1) ? bk : bv);
  const int bm0 = blockIdx.x * 128, bn0 = blockIdx.y * 128;
  const f32x4 zf = {0.f, 0.f, 0.f, 0.f};
  f32x4 acc[4][4];
#pragma unroll
  for (int m = 0; m < 4; ++m)
#pragma unroll
    for (int n = 0; n < 4; ++n) acc[m][n] = zf;
  gemm_core(xb, W, bm0, bn0, ldsA, ldsB, acc);
  const int tid = threadIdx.x, l = tid & 63, lr = l & 15, lk = l >> 4;
  const int w = tid >> 6, wr = w >> 1, wc = w & 1;
  float bcol[4];
#pragma unroll
  for (int n = 0; n < 4; ++n) bcol[n] = bias[bn0 + wc * 64 + n * 16 + lr];
  if (z < 2) {
    u16* outp = z ? Kb : Qb;
#pragma unroll
    for (int m = 0; m < 4; ++m)
#pragma unroll
      for (int n = 0; n < 4; ++n)
#pragma unroll
        for (int r = 0; r < 4; ++r) {
          int row = bm0 + wr * 64 + m * 16 + lk * 4 + r;
          int col = bn0 + wc * 64 + n * 16 + lr;
          outp[(size_t)row * 1024 + col] = f2bf(acc[m][n][r] + bcol[n]);
        }
  } else {
#pragma unroll
    for (int m = 0; m < 4; ++m)
#pragma unroll
      for (int n = 0; n < 4; ++n) {
        int row = bm0 + wr * 64 + m * 16 + lk * 4;   // key base (r = 0..3)
        int col = bn0 + wc * 64 + n * 16 + lr;
        int b = row >> 11, sf = row & 2047, hh = col >> 6, hd = col & 63;
        int t = sf >> 6, kin = sf & 63;
        int ks = kin >> 4, hiv = (kin >> 3) & 1, j0 = kin & 7;
        int vhalf = hd >> 5, lq = hd & 31;
        u16x4 o;
#pragma unroll
        for (int r = 0; r < 4; ++r) o[r] = f2bf(acc[m][n][r] + bcol[n]);
        size_t addr = (size_t)(b * 16 + hh) * 131072 +
                      (size_t)(((t * 4 + ks) * 2 + vhalf)) * 512 +
                      ((hiv << 5) + lq) * 8 + j0;
        *(u16x4*)(Vf + addr) = o;
      }
  }
}

// --------------------------------------------- output projection
__global__ __launch_bounds__(256) void proj_gemm(const u16* __restrict__ ctx,
    const u16* __restrict__ wo, const float* __restrict__ bo, float* __restrict__ out) {
  __shared__ u16 ldsA[3 * 4096];
  __shared__ u16 ldsB[3 * 4096];
  const int bm0 = blockIdx.x * 128, bn0 = blockIdx.y * 128;
  const f32x4 zf = {0.f, 0.f, 0.f, 0.f};
  f32x4 acc[4][4];
#pragma unroll
  for (int m = 0; m < 4; ++m)
#pragma unroll
    for (int n = 0; n < 4; ++n) acc[m][n] = zf;
  gemm_core(ctx, wo, bm0, bn0, ldsA, ldsB, acc);
  const int tid = threadIdx.x, l = tid & 63, lr = l & 15, lk = l >> 4;
  const int w = tid >> 6, wr = w >> 1, wc = w & 1;
  float bcol[4];
#pragma unroll
  for (int n = 0; n < 4; ++n) bcol[n] = bo[bn0 + wc * 64 + n * 16 + lr];
#pragma unroll
  for (int m = 0; m < 4; ++m)
#pragma unroll
    for (int n = 0; n < 4; ++n)
#pragma unroll
      for (int r = 0; r < 4; ++r) {
        int row = bm0 + wr * 64 + m * 16 + lk * 4 + r;
        int col = bn0 + wc * 64 + n * 16 + lr;
        out[(size_t)row * 1024 + col] = acc[m][n][r] + bcol[n];
      }
}

// --------------------------------------------- RMSNorm + RoPE -> fragment layouts
__global__ __launch_bounds__(256) void rmsrope(const u16* __restrict__ Qb,
    const u16* __restrict__ Kb, const float* __restrict__ gq, const float* __restrict__ gk,
    const float* __restrict__ fc, const float* __restrict__ fs,
    u16* __restrict__ Qf, u16* __restrict__ Kf) {
  const int row = blockIdx.x;
  const int which = blockIdx.y;
  const u16* src = (which ? Kb : Qb) + (size_t)row * 1024;
  const float* g = which ? gk : gq;
  const int t = threadIdx.x;
  u16x4 raw = *(const u16x4*)(src + t * 4);
  float v0 = bf2f(raw[0]), v1 = bf2f(raw[1]), v2 = bf2f(raw[2]), v3 = bf2f(raw[3]);
  float ss = v0 * v0 + v1 * v1 + v2 * v2 + v3 * v3;
#pragma unroll
  for (int mm = 1; mm < 64; mm <<= 1) ss += __shfl_xor(ss, mm);
  __shared__ float red[4];
  if ((t & 63) == 0) red[t >> 6] = ss;
  __syncthreads();
  float rstd = rsqrtf((red[0] + red[1] + red[2] + red[3]) * (1.0f / 1024.0f) + 1e-6f);
  if (!which) rstd *= 0.18033688011112042f;   // 0.125 * log2(e) folded into q
  int d = t * 4, hh = d >> 6, dh = d & 63, p = dh >> 1;
  int s = row & 2047, b = row >> 11;
  float c0 = fc[(s << 5) + p], s0 = fs[(s << 5) + p];
  float c1 = fc[(s << 5) + p + 1], s1 = fs[(s << 5) + p + 1];
  float x0 = v0 * rstd * g[d];
  float x1 = v1 * rstd * g[d + 1];
  float x2 = v2 * rstd * g[d + 2];
  float x3 = v3 * rstd * g[d + 3];
  u16x4 o;
  o[0] = f2bf(x0 * c0 - x1 * s0);
  o[1] = f2bf(x0 * s0 + x1 * c0);
  o[2] = f2bf(x2 * c1 - x3 * s1);
  o[3] = f2bf(x2 * s1 + x3 * c1);
  const size_t base = (size_t)(b * 16 + hh) * 131072;
  const int hs = dh >> 4, hi = (dh >> 3) & 1, j0 = dh & 7;
  size_t addr;
  if (!which) {
    addr = base + (size_t)((s >> 5) * 4 + hs) * 512 + ((hi << 5) + (s & 31)) * 8 + j0;
  } else {
    addr = base + (size_t)(((s >> 6) * 4 + hs) * 2 + ((s >> 5) & 1)) * 512 +
           ((hi << 5) + (s & 31)) * 8 + j0;
  }
  *(u16x4*)((which ? Kf : Qf) + addr) = o;
}

// --------------------------------------------- flash attention (non-causal)
// 512 blocks x 256 thr (4 waves). R17 = R16's LDS-K + cross-iteration ILP:
// QK(t+1) is issued BEFORE softmax+PV(t) each iteration, so the independent
// QK MFMA chain interleaves (compile-time scheduling) with sm_pv's exp2 and
// exchange VALU. R15's version of this lost its gain to register pressure
// (~240 regs, occupancy halved); with K in LDS and single-buffered V the
// live set stays ~170 incl. accumulators -> 2 blocks/CU preserved.
__global__ __launch_bounds__(256) void attn_kernel(const u16* __restrict__ Qf,
    const u16* __restrict__ Kf, const u16* __restrict__ Vf, u16* __restrict__ ctx) {
  __shared__ u16 Kbuf[3][4096];    // 3 x 8KB K tiles, linear copy of K-frag
  const int tid = threadIdx.x;
  const int w = tid >> 6, l = tid & 63;
  const int lq = l & 31, hi = l >> 5;
  const bool hiB = (hi != 0);
  const int id = blockIdx.x;
  const int qt = (id >> 3) & 15;
  const int hb = (id & 7) | ((id >> 7) << 3);
  const int h = hb & 15, b = hb >> 4;
  const int bh = b * 16 + h;
  const u16* Qp = Qf + (size_t)bh * 131072;
  const u16* Kp = Kf + (size_t)bh * 131072;
  const u16* Vp = Vf + (size_t)bh * 131072;
  bf16x8 qf[4];
#pragma unroll
  for (int hs = 0; hs < 4; ++hs)
    qf[hs] = *(const bf16x8*)(Qp + (size_t)((qt * 4 + w) * 4 + hs) * 512 + l * 8);

  auto stageK = [&](int t, u16* dst) {   // 2 gload_lds per thread (8KB/block)
    GLOAD16(Kp + (size_t)t * 4096 + tid * 8, dst + tid * 8);
    GLOAD16(Kp + (size_t)t * 4096 + 2048 + tid * 8, dst + 2048 + tid * 8);
  };
  auto ldV = [&](int t, bf16x8* vr) {    // 8 direct global loads per wave
#pragma unroll
    for (int i = 0; i < 8; ++i)
      vr[i] = *(const bf16x8*)(Vp + ((size_t)t * 8 + i) * 512 + l * 8);
  };

  const f32x16 z16 = {0,0,0,0, 0,0,0,0, 0,0,0,0, 0,0,0,0};
  f32x16 O0 = z16, O1 = z16;
  float lsum = 0.f;

  auto qk_lds = [&](const u16* Kb_, f32x16& s0, f32x16& s1) {
    s0 = z16; s1 = z16;
    __builtin_amdgcn_s_setprio(1);
#pragma unroll
    for (int hs = 0; hs < 4; ++hs) {
      bf16x8 k0 = *(const bf16x8*)(Kb_ + (hs * 2 + 0) * 512 + l * 8);
      bf16x8 k1 = *(const bf16x8*)(Kb_ + (hs * 2 + 1) * 512 + l * 8);
      s0 = __builtin_amdgcn_mfma_f32_32x32x16_bf16(k0, qf[hs], s0, 0, 0, 0);
      s1 = __builtin_amdgcn_mfma_f32_32x32x16_bf16(k1, qf[hs], s1, 0, 0, 0);
    }
    __builtin_amdgcn_s_setprio(0);
  };

  auto sm_pv = [&](const bf16x8* vr, f32x16& sc0, f32x16& sc1) {
    u32 pk0[8], pk1[8];
    float tm[8];
#pragma unroll
    for (int m = 0; m < 8; ++m) {
      float a0 = __builtin_amdgcn_exp2f(sc0[2 * m]);
      float a1 = __builtin_amdgcn_exp2f(sc0[2 * m + 1]);
      float c0 = __builtin_amdgcn_exp2f(sc1[2 * m]);
      float c1 = __builtin_amdgcn_exp2f(sc1[2 * m + 1]);
      tm[m] = (a0 + a1) + (c0 + c1);
      bf16x2 pA; pA[0] = (__bf16)a0; pA[1] = (__bf16)a1;
      bf16x2 pC; pC[0] = (__bf16)c0; pC[1] = (__bf16)c1;
      pk0[m] = __builtin_bit_cast(u32, pA);
      pk1[m] = __builtin_bit_cast(u32, pC);
    }
    float rs = ((tm[0] + tm[1]) + (tm[2] + tm[3])) +
               ((tm[4] + tm[5]) + (tm[6] + tm[7]));   // tree, short dep chain
    rs += __shfl_xor(rs, 32);
    lsum += rs;
    // direction-proof half exchange (R7): pb[ks] elem j = P[16ks+8hi+j][lq]
    auto xchg = [&](u32 X, u32 Y, u32& wlo, u32& whi) {
      u32 s1v = hiB ? X : Y;
      u32 r = (u32)__shfl_xor((int)s1v, 32);
      wlo = hiB ? r : X;
      whi = hiB ? Y : r;
    };
    bf16x8 pb[4];
    {
      u32 w0, w1, w2, w3;
      xchg(pk0[0], pk0[2], w0, w2);
      xchg(pk0[1], pk0[3], w1, w3);
      u32x4 pw = {w0, w1, w2, w3};
      pb[0] = __builtin_bit_cast(bf16x8, pw);
      xchg(pk0[4], pk0[6], w0, w2);
      xchg(pk0[5], pk0[7], w1, w3);
      u32x4 pw1 = {w0, w1, w2, w3};
      pb[1] = __builtin_bit_cast(bf16x8, pw1);
      xchg(pk1[0], pk1[2], w0, w2);
      xchg(pk1[1], pk1[3], w1, w3);
      u32x4 pw2 = {w0, w1, w2, w3};
      pb[2] = __builtin_bit_cast(bf16x8, pw2);
      xchg(pk1[4], pk1[6], w0, w2);
      xchg(pk1[5], pk1[7], w1, w3);
      u32x4 pw3 = {w0, w1, w2, w3};
      pb[3] = __builtin_bit_cast(bf16x8, pw3);
    }
    __builtin_amdgcn_s_setprio(1);
#pragma unroll
    for (int ks = 0; ks < 4; ++ks) {
      O0 = __builtin_amdgcn_mfma_f32_32x32x16_bf16(vr[ks * 2 + 0], pb[ks], O0, 0, 0, 0);
      O1 = __builtin_amdgcn_mfma_f32_32x32x16_bf16(vr[ks * 2 + 1], pb[ks], O1, 0, 0, 0);
    }
    __builtin_amdgcn_s_setprio(0);
  };

  bf16x8 vV[8];
  f32x16 scA0, scA1, scB0, scB1;
  u16* pA = &Kbuf[0][0];
  u16* pB = &Kbuf[1][0];
  u16* pC = &Kbuf[2][0];
  stageK(0, pA);
  stageK(1, pB);
  stageK(2, pC);
  asm volatile("s_waitcnt vmcnt(2)" ::: "memory");   // K0,K1 landed; K2 in flight
  __builtin_amdgcn_s_barrier();
  __builtin_amdgcn_sched_barrier(0);
  qk_lds(pA, scA0, scA1);                            // scores for tile 0
#pragma unroll 1
  for (int dt = 0; dt < 16; ++dt) {
    const int t = dt * 2;
    {   // iter t: scores(t) in scA; compute QK(t+1) -> scB, then sm_pv(t)
      __builtin_amdgcn_s_barrier();
      __builtin_amdgcn_sched_barrier(0);
      ldV(t, vV);
      if (t + 3 < 32) stageK(t + 3, pA);   // buf (t%3): last read was qk(t)
      qk_lds(pB, scB0, scB1);              // buf (t+1)%3, drained via V(t-1) wait
      sm_pv(vV, scA0, scA1);               // V-wait leaves stageK in flight
    }
    {   // iter t+1: scores in scB; QK(t+2) -> scA, then sm_pv(t+1)
      __builtin_amdgcn_s_barrier();
      __builtin_amdgcn_sched_barrier(0);
      ldV(t + 1, vV);
      if (t + 4 < 32) stageK(t + 4, pB);
      if (t + 2 < 32) qk_lds(pC, scA0, scA1);
      sm_pv(vV, scB0, scB1);
    }
    u16* tmp = pA; pA = pC; pC = pB; pB = tmp;   // (A,B,C) <- (C,A,B)
  }
  float inv = 1.0f / lsum;
  const int q0 = qt * 128 + w * 32;
  const size_t rowoff = ((size_t)(b * 2048 + q0 + lq)) * 1024 + h * 64;
#pragma unroll
  for (int g = 0; g < 4; ++g) {                 // hd = 8g + 4hi + rr (+32 for O1)
    u16x4 oa, ob;
#pragma unroll
    for (int rr = 0; rr < 4; ++rr) {
      oa[rr] = f2bf(O0[4 * g + rr] * inv);
      ob[rr] = f2bf(O1[4 * g + rr] * inv);
    }
    *(u16x4*)(ctx + rowoff + 8 * g + 4 * hi) = oa;
    *(u16x4*)(ctx + rowoff + 32 + 8 * g + 4 * hi) = ob;
  }
}

// ---------------------------------------------------------------- launch
extern "C" void kernel_launch(void* const* d_in, const int* in_sizes, int n_in,
                              void* d_out, int out_size, void* d_ws, size_t ws_size,
                              hipStream_t stream) {
  (void)in_sizes; (void)n_in; (void)out_size; (void)ws_size;
  const float* x  = (const float*)d_in[0];
  const float* Wq = (const float*)d_in[1];
  const float* bq = (const float*)d_in[2];
  const float* Wk = (const float*)d_in[3];
  const float* bk = (const float*)d_in[4];
  const float* Wv = (const float*)d_in[5];
  const float* bv = (const float*)d_in[6];
  const float* Wo = (const float*)d_in[7];
  const float* bo = (const float*)d_in[8];
  const float* gq = (const float*)d_in[9];
  const float* gk = (const float*)d_in[10];
  const float* fc = (const float*)d_in[11];
  const float* fs = (const float*)d_in[12];
  float* out = (float*)d_out;
  char* ws = (char*)d_ws;
  u16*  xb  = (u16*)(ws + 0);           //  8 MB  x bf16 [4096][1024]
  u16*  wqb = (u16*)(ws + 8388608);     //  2 MB each, contiguous x4
  u16*  wkb = (u16*)(ws + 10485760);
  u16*  wvb = (u16*)(ws + 12582912);
  u16*  wob = (u16*)(ws + 14680064);
  u16*  Qfb = (u16*)(ws + 16777216);    //  8 MB bf16 pre-norm q rows
  u16*  Kfb = (u16*)(ws + 25165824);    //  8 MB pre-norm k rows
  u16*  Qfr = (u16*)(ws + 33554432);    //  8 MB Q fragment-major
  u16*  Kfr = (u16*)(ws + 41943040);    //  8 MB K fragment-major
  u16*  Vfr = (u16*)(ws + 50331648);    //  8 MB V fragment-major
  u16*  ctx = (u16*)(ws + 58720256);    //  8 MB bf16 [B,S,D]

  f2ball_kernel<<<8192, 256, 0, stream>>>(x, Wq, Wk, Wv, Wo, xb, wqb);
  qkv_gemm<<<dim3(32, 8, 3), 256, 0, stream>>>(xb, wqb, wkb, wvb, bq, bk, bv, Qfb, Kfb, Vfr);
  rmsrope<<<dim3(4096, 2), 256, 0, stream>>>(Qfb, Kfb, gq, gk, fc, fs, Qfr, Kfr);
  attn_kernel<<<512, 256, 0, stream>>>(Qfr, Kfr, Vfr, ctx);
  proj_gemm<<<dim3(32, 8), 256, 0, stream>>>(ctx, wob, bo, out);
}